// Round 1
// baseline (69801.819 us; speedup 1.0000x reference)
//
#include <hip/hip_runtime.h>
#include <stdint.h>

typedef unsigned short ushort_t;
typedef __attribute__((ext_vector_type(8))) short short8;
typedef __attribute__((ext_vector_type(4))) float f32x4;

#define T_SEQ 4096
#define IN_SZ 512
#define H1 1024
#define H2 2048
#define G1 (4*H1)   // 4096
#define G2 (4*H2)   // 8192
#define OUT_SZ 512
#define L1OUT 1024

__device__ __forceinline__ ushort_t f32_to_bf16(float f) {
    union { float f; uint32_t u; } x; x.f = f;
    uint32_t u = x.u;
    uint32_t r = (u + 0x7fffu + ((u >> 16) & 1u)) >> 16;
    return (ushort_t)r;
}
__device__ __forceinline__ float bf16_lo(uint32_t p) {
    union { uint32_t u; float f; } x; x.u = p << 16; return x.f;
}
__device__ __forceinline__ float bf16_hi(uint32_t p) {
    union { uint32_t u; float f; } x; x.u = p & 0xffff0000u; return x.f;
}
__device__ __forceinline__ float bf16_val(ushort_t v) {
    union { uint32_t u; float f; } x; x.u = ((uint32_t)v) << 16; return x.f;
}
__device__ __forceinline__ float sigmoidf(float x) {
    return 1.0f / (1.0f + expf(-x));
}

// ---------------- f32 -> bf16 conversion ----------------
__global__ __launch_bounds__(256) void cvt_bf16_kernel(const float* __restrict__ in,
                                                       ushort_t* __restrict__ out, int n) {
    int i = blockIdx.x * 256 + threadIdx.x;
    int stride = gridDim.x * 256;
    for (; i < n; i += stride) out[i] = f32_to_bf16(in[i]);
}

// ---------------- bf16 MFMA GEMM: C[M,N] = A[M,K] * B[N,K]^T + bias_a[n] + bias_b[n] ----------------
// A row-major [M,K] bf16, B row-major [N,K] bf16 (i.e. B^T input). 64x64 tile/block, 4 waves.
// Fragment layouts (verified m89/m91/m120): A/B: idx=lane&15, k=(lane>>4)*8+j ; C/D: col=lane&15, row=(lane>>4)*4+reg
template <bool OUT_BF16>
__global__ __launch_bounds__(256) void gemm_bt_kernel(const ushort_t* __restrict__ A,
                                                      const ushort_t* __restrict__ B,
                                                      float* __restrict__ Cf,
                                                      ushort_t* __restrict__ Cb,
                                                      const float* __restrict__ bias_a,
                                                      const float* __restrict__ bias_b,
                                                      int M, int N, int K) {
    int tid  = threadIdx.x;
    int wave = tid >> 6;
    int lane = tid & 63;
    int l15  = lane & 15;
    int quad = lane >> 4;
    int m0 = blockIdx.y * 64 + wave * 16;
    int n0 = blockIdx.x * 64;

    const ushort_t* pa = A + (size_t)(m0 + l15) * K + quad * 8;
    f32x4 acc[4];
    #pragma unroll
    for (int i = 0; i < 4; ++i) acc[i] = (f32x4){0.f, 0.f, 0.f, 0.f};

    for (int kc = 0; kc < K; kc += 32) {
        short8 a = *(const short8*)(pa + kc);
        #pragma unroll
        for (int nf = 0; nf < 4; ++nf) {
            const ushort_t* pb = B + (size_t)(n0 + nf * 16 + l15) * K + quad * 8 + kc;
            short8 b = *(const short8*)pb;
            acc[nf] = __builtin_amdgcn_mfma_f32_16x16x32_bf16(a, b, acc[nf], 0, 0, 0);
        }
    }

    int rbase = quad * 4;
    #pragma unroll
    for (int nf = 0; nf < 4; ++nf) {
        int n = n0 + nf * 16 + l15;
        float bb = bias_a[n] + bias_b[n];
        #pragma unroll
        for (int r = 0; r < 4; ++r) {
            int m = m0 + rbase + r;
            float v = acc[nf][r] + bb;
            if (OUT_BF16) Cb[(size_t)m * N + n] = f32_to_bf16(v);
            else          Cf[(size_t)m * N + n] = v;
        }
    }
}

// ---------------- Persistent LSTM recurrence ----------------
// 256 blocks x 256 threads, each block owns UNITS hidden units.
// Communication: comm words (u32) + per-block flags, relaxed agent-scope atomics (no cache-invalidating fences).
// COMM_BF16: comm[t*H/2 + w] packs 2 bf16 (full sequence kept).  else: comm[(t&1)*H + j] = f32 (double buffer).
template <int H, int UNITS, int TPD, bool PRE_BF16, bool COMM_BF16>
__global__ __launch_bounds__(256) void lstm_rec_kernel(const void* __restrict__ pre_,
                                                       const ushort_t* __restrict__ whh,
                                                       uint32_t* __restrict__ comm,
                                                       int* __restrict__ flags,
                                                       int T) {
    constexpr int NB    = H / UNITS;             // 256 blocks
    constexpr int WORDS = COMM_BF16 ? H / 2 : H; // comm words per step
    constexpr int WPT   = WORDS / 256;
    constexpr int DOTS  = UNITS * 4;
    constexpr int ITERS = H / (TPD * 8);

    __shared__ float h_lds[H];
    __shared__ float dots_lds[DOTS];
    __shared__ float h_own[UNITS];

    int tid = threadIdx.x;
    int blk = blockIdx.x;
    int dot_id  = tid / TPD;
    int lane_in = tid % TPD;
    int u = dot_id >> 2;
    int g = dot_id & 3;
    int J = blk * UNITS + u;   // global unit this dot belongs to
    const ushort_t* wrow = whh + (size_t)(g * H + J) * H;

    float c_reg = 0.0f;        // valid for tid < UNITS

    for (int t = 0; t < T; ++t) {
        float dot = 0.0f;
        if (t > 0) {
            // wait for all blocks to have published h[t-1]
            if (tid < NB) {
                while (__hip_atomic_load(&flags[tid], __ATOMIC_RELAXED,
                                         __HIP_MEMORY_SCOPE_AGENT) < t) {
                    __builtin_amdgcn_s_sleep(1);
                }
            }
            __syncthreads();
            // load h[t-1] into LDS (cache-bypassing loads)
            size_t cbase = COMM_BF16 ? (size_t)(t - 1) * WORDS
                                     : (size_t)((t - 1) & 1) * WORDS;
            #pragma unroll
            for (int w0 = 0; w0 < WPT; ++w0) {
                int w = tid * WPT + w0;
                uint32_t v = __hip_atomic_load(&comm[cbase + w], __ATOMIC_RELAXED,
                                               __HIP_MEMORY_SCOPE_AGENT);
                if (COMM_BF16) {
                    h_lds[2 * w]     = bf16_lo(v);
                    h_lds[2 * w + 1] = bf16_hi(v);
                } else {
                    union { uint32_t u; float f; } x; x.u = v;
                    h_lds[w] = x.f;
                }
            }
            __syncthreads();
            // partial dot product: row (g*H + J) of whh against h[t-1]
            #pragma unroll
            for (int it = 0; it < ITERS; ++it) {
                int k = it * (TPD * 8) + lane_in * 8;
                uint4 wv = *(const uint4*)(wrow + k);
                dot = fmaf(bf16_lo(wv.x), h_lds[k + 0], dot);
                dot = fmaf(bf16_hi(wv.x), h_lds[k + 1], dot);
                dot = fmaf(bf16_lo(wv.y), h_lds[k + 2], dot);
                dot = fmaf(bf16_hi(wv.y), h_lds[k + 3], dot);
                dot = fmaf(bf16_lo(wv.z), h_lds[k + 4], dot);
                dot = fmaf(bf16_hi(wv.z), h_lds[k + 5], dot);
                dot = fmaf(bf16_lo(wv.w), h_lds[k + 6], dot);
                dot = fmaf(bf16_hi(wv.w), h_lds[k + 7], dot);
            }
        }
        // reduce within TPD-lane group
        #pragma unroll
        for (int off = TPD / 2; off > 0; off >>= 1)
            dot += __shfl_down(dot, off, TPD);
        if (lane_in == 0) dots_lds[dot_id] = dot;
        __syncthreads();

        // gate update: one thread per unit
        if (tid < UNITS) {
            int uu = tid;
            int JJ = blk * UNITS + uu;
            size_t pb = (size_t)t * (4 * H);
            float p0, p1, p2, p3;
            if (PRE_BF16) {
                const ushort_t* pp = (const ushort_t*)pre_;
                p0 = bf16_val(pp[pb + 0 * H + JJ]);
                p1 = bf16_val(pp[pb + 1 * H + JJ]);
                p2 = bf16_val(pp[pb + 2 * H + JJ]);
                p3 = bf16_val(pp[pb + 3 * H + JJ]);
            } else {
                const float* pp = (const float*)pre_;
                p0 = pp[pb + 0 * H + JJ];
                p1 = pp[pb + 1 * H + JJ];
                p2 = pp[pb + 2 * H + JJ];
                p3 = pp[pb + 3 * H + JJ];
            }
            float iv = sigmoidf(p0 + dots_lds[uu * 4 + 0]);
            float fv = sigmoidf(p1 + dots_lds[uu * 4 + 1]);
            float gv = tanhf  (p2 + dots_lds[uu * 4 + 2]);
            float ov = sigmoidf(p3 + dots_lds[uu * 4 + 3]);
            c_reg = fv * c_reg + iv * gv;
            float h = ov * tanhf(c_reg);
            if (COMM_BF16) {
                h_own[uu] = h;
            } else {
                union { float f; uint32_t u; } x; x.f = h;
                __hip_atomic_store(&comm[(size_t)(t & 1) * WORDS + JJ], x.u,
                                   __ATOMIC_RELAXED, __HIP_MEMORY_SCOPE_AGENT);
            }
        }
        if (COMM_BF16) {
            __syncthreads();
            if (tid < UNITS / 2) {
                uint32_t lo = f32_to_bf16(h_own[2 * tid]);
                uint32_t hi = f32_to_bf16(h_own[2 * tid + 1]);
                uint32_t w  = lo | (hi << 16);
                __hip_atomic_store(&comm[(size_t)t * WORDS + blk * (UNITS / 2) + tid], w,
                                   __ATOMIC_RELAXED, __HIP_MEMORY_SCOPE_AGENT);
            }
        }
        // __syncthreads drains vmcnt(0) for every thread (compiler-guaranteed) -> all h stores
        // are complete (sc1 write-through to LLC) before the flag store below issues.
        __syncthreads();
        if (tid == 0)
            __hip_atomic_store(&flags[blk], t + 1, __ATOMIC_RELAXED,
                               __HIP_MEMORY_SCOPE_AGENT);
    }
}

// ---------------- small matvec: out[j] = W[j,:K] . x + bias[j], one wave per output ----------------
__global__ __launch_bounds__(256) void linear_vec_kernel(const float* __restrict__ W,
                                                         const float* __restrict__ bias,
                                                         const float* __restrict__ x,
                                                         float* __restrict__ out,
                                                         int N, int K) {
    int wave = threadIdx.x >> 6;
    int lane = threadIdx.x & 63;
    int j = blockIdx.x * 4 + wave;
    if (j >= N) return;
    const float* wr = W + (size_t)j * K;
    float s = 0.0f;
    for (int k = lane; k < K; k += 64) s += wr[k] * x[k];
    #pragma unroll
    for (int off = 32; off > 0; off >>= 1) s += __shfl_down(s, off, 64);
    if (lane == 0) out[j] = s + bias[j];
}

extern "C" void kernel_launch(void* const* d_in, const int* in_sizes, int n_in,
                              void* d_out, int out_size, void* d_ws, size_t ws_size,
                              hipStream_t stream) {
    const float* x_f    = (const float*)d_in[0];
    const float* wih1_f = (const float*)d_in[1];
    const float* whh1_f = (const float*)d_in[2];
    const float* bih1   = (const float*)d_in[3];
    const float* bhh1   = (const float*)d_in[4];
    const float* wih2_f = (const float*)d_in[5];
    const float* whh2_f = (const float*)d_in[6];
    const float* bih2   = (const float*)d_in[7];
    const float* bhh2   = (const float*)d_in[8];
    const float* wl1    = (const float*)d_in[9];
    const float* bl1    = (const float*)d_in[10];
    const float* wl2    = (const float*)d_in[11];
    const float* bl2    = (const float*)d_in[12];

    uint8_t* base = (uint8_t*)d_ws;
    size_t off = 0;
    auto alloc = [&](size_t bytes) { size_t o = off; off = (off + bytes + 255) & ~(size_t)255; return o; };

    size_t pre1_off  = alloc((size_t)T_SEQ * G1 * 4);   // f32 [T,4096]
    size_t pre2_off  = alloc((size_t)T_SEQ * G2 * 2);   // bf16 [T,8192]
    size_t h1seq_off = alloc((size_t)T_SEQ * H1 * 2);   // bf16 [T,1024] (= comm1)
    size_t whh1_off  = alloc((size_t)G1 * H1 * 2);
    size_t whh2_off  = alloc((size_t)G2 * H2 * 2);
    size_t wih1_off  = alloc((size_t)G1 * IN_SZ * 2);
    size_t wih2_off  = alloc((size_t)G2 * H1 * 2);
    size_t xb_off    = alloc((size_t)T_SEQ * IN_SZ * 2);
    size_t h2buf_off = alloc((size_t)2 * H2 * 4);       // f32 double buffer (= comm2)
    size_t p1_off    = alloc((size_t)L1OUT * 4);
    size_t flags_off = alloc((size_t)512 * 4);          // flags1[256] ++ flags2[256]

    float*    pre1  = (float*)(base + pre1_off);
    ushort_t* pre2  = (ushort_t*)(base + pre2_off);
    ushort_t* h1seq = (ushort_t*)(base + h1seq_off);
    ushort_t* whh1b = (ushort_t*)(base + whh1_off);
    ushort_t* whh2b = (ushort_t*)(base + whh2_off);
    ushort_t* wih1b = (ushort_t*)(base + wih1_off);
    ushort_t* wih2b = (ushort_t*)(base + wih2_off);
    ushort_t* xb    = (ushort_t*)(base + xb_off);
    float*    h2buf = (float*)(base + h2buf_off);
    float*    p1    = (float*)(base + p1_off);
    int*      flags1 = (int*)(base + flags_off);
    int*      flags2 = flags1 + 256;

    // zero the sync flags (ws is poisoned 0xAA before every launch)
    hipMemsetAsync(flags1, 0, 512 * sizeof(int), stream);

    // f32 -> bf16 conversions
    cvt_bf16_kernel<<<2048, 256, 0, stream>>>(x_f,    xb,    T_SEQ * IN_SZ);
    cvt_bf16_kernel<<<2048, 256, 0, stream>>>(wih1_f, wih1b, G1 * IN_SZ);
    cvt_bf16_kernel<<<2048, 256, 0, stream>>>(whh1_f, whh1b, G1 * H1);
    cvt_bf16_kernel<<<2048, 256, 0, stream>>>(wih2_f, wih2b, G2 * H1);
    cvt_bf16_kernel<<<4096, 256, 0, stream>>>(whh2_f, whh2b, G2 * H2);

    // pre1 = x @ wih1^T + (bih1 + bhh1)   [f32 out]
    {
        dim3 grid(G1 / 64, T_SEQ / 64);
        gemm_bt_kernel<false><<<grid, 256, 0, stream>>>(xb, wih1b, pre1, (ushort_t*)nullptr,
                                                        bih1, bhh1, T_SEQ, G1, IN_SZ);
    }
    // layer-1 recurrence -> h1seq (bf16, full sequence)
    lstm_rec_kernel<H1, 4, 16, false, true><<<256, 256, 0, stream>>>(
        pre1, whh1b, (uint32_t*)h1seq, flags1, T_SEQ);

    // pre2 = h1 @ wih2^T + (bih2 + bhh2)  [bf16 out]
    {
        dim3 grid(G2 / 64, T_SEQ / 64);
        gemm_bt_kernel<true><<<grid, 256, 0, stream>>>(h1seq, wih2b, (float*)nullptr, pre2,
                                                       bih2, bhh2, T_SEQ, G2, H1);
    }
    // layer-2 recurrence -> h2buf (f32 double buffer); final h2 at parity (T-1)&1 == 1
    lstm_rec_kernel<H2, 8, 8, true, false><<<256, 256, 0, stream>>>(
        pre2, whh2b, (uint32_t*)h2buf, flags2, T_SEQ);

    // p1 = wl1 . h2_final + bl1 ; out = wl2 . p1 + bl2
    linear_vec_kernel<<<L1OUT / 4, 256, 0, stream>>>(wl1, bl1, h2buf + H2, p1, L1OUT, H2);
    linear_vec_kernel<<<OUT_SZ / 4, 256, 0, stream>>>(wl2, bl2, p1, (float*)d_out, OUT_SZ, L1OUT);

    (void)in_sizes; (void)n_in; (void)out_size; (void)ws_size;
}

// Round 2
// 46888.608 us; speedup vs baseline: 1.4887x; 1.4887x over previous
//
#include <hip/hip_runtime.h>
#include <stdint.h>

typedef unsigned short ushort_t;
typedef __attribute__((ext_vector_type(8))) short short8;
typedef __attribute__((ext_vector_type(4))) float f32x4;

#define T_SEQ 4096
#define IN_SZ 512
#define H1 1024
#define H2 2048
#define G1 (4*H1)   // 4096
#define G2 (4*H2)   // 8192
#define OUT_SZ 512
#define L1OUT 1024

__device__ __forceinline__ ushort_t f32_to_bf16(float f) {
    union { float f; uint32_t u; } x; x.f = f;
    uint32_t u = x.u;
    uint32_t r = (u + 0x7fffu + ((u >> 16) & 1u)) >> 16;
    return (ushort_t)r;
}
__device__ __forceinline__ float bf16_lo(uint32_t p) {
    union { uint32_t u; float f; } x; x.u = p << 16; return x.f;
}
__device__ __forceinline__ float bf16_hi(uint32_t p) {
    union { uint32_t u; float f; } x; x.u = p & 0xffff0000u; return x.f;
}
__device__ __forceinline__ float bf16_val(ushort_t v) {
    union { uint32_t u; float f; } x; x.u = ((uint32_t)v) << 16; return x.f;
}
__device__ __forceinline__ float sigmoidf(float x) {
    return 1.0f / (1.0f + expf(-x));
}

// ---------------- f32 -> bf16 conversion ----------------
__global__ __launch_bounds__(256) void cvt_bf16_kernel(const float* __restrict__ in,
                                                       ushort_t* __restrict__ out, int n) {
    int i = blockIdx.x * 256 + threadIdx.x;
    int stride = gridDim.x * 256;
    for (; i < n; i += stride) out[i] = f32_to_bf16(in[i]);
}

// ---------------- bf16 MFMA GEMM: C[M,N] = A[M,K] * B[N,K]^T + bias_a[n] + bias_b[n] ----------------
template <bool OUT_BF16>
__global__ __launch_bounds__(256) void gemm_bt_kernel(const ushort_t* __restrict__ A,
                                                      const ushort_t* __restrict__ B,
                                                      float* __restrict__ Cf,
                                                      ushort_t* __restrict__ Cb,
                                                      const float* __restrict__ bias_a,
                                                      const float* __restrict__ bias_b,
                                                      int M, int N, int K) {
    int tid  = threadIdx.x;
    int wave = tid >> 6;
    int lane = tid & 63;
    int l15  = lane & 15;
    int quad = lane >> 4;
    int m0 = blockIdx.y * 64 + wave * 16;
    int n0 = blockIdx.x * 64;

    const ushort_t* pa = A + (size_t)(m0 + l15) * K + quad * 8;
    f32x4 acc[4];
    #pragma unroll
    for (int i = 0; i < 4; ++i) acc[i] = (f32x4){0.f, 0.f, 0.f, 0.f};

    for (int kc = 0; kc < K; kc += 32) {
        short8 a = *(const short8*)(pa + kc);
        #pragma unroll
        for (int nf = 0; nf < 4; ++nf) {
            const ushort_t* pb = B + (size_t)(n0 + nf * 16 + l15) * K + quad * 8 + kc;
            short8 b = *(const short8*)pb;
            acc[nf] = __builtin_amdgcn_mfma_f32_16x16x32_bf16(a, b, acc[nf], 0, 0, 0);
        }
    }

    int rbase = quad * 4;
    #pragma unroll
    for (int nf = 0; nf < 4; ++nf) {
        int n = n0 + nf * 16 + l15;
        float bb = bias_a[n] + bias_b[n];
        #pragma unroll
        for (int r = 0; r < 4; ++r) {
            int m = m0 + rbase + r;
            float v = acc[nf][r] + bb;
            if (OUT_BF16) Cb[(size_t)m * N + n] = f32_to_bf16(v);
            else          Cf[(size_t)m * N + n] = v;
        }
    }
}

// ---------------- Persistent LSTM recurrence, register-resident weights ----------------
// 256 blocks x 256 threads (1 block/CU). Block owns UNITS units; thread (dg,ln) covers
// all 4 gates of unit (blk*UNITS+dg) over k-chunk {ln*4 + j*LANES*4}. h[t-1] staged in LDS
// (conflict-free stride-1). Dot reduced via shfl within LANES group; lane 0 owns c, does
// gates, publishes h via relaxed agent-scope atomics (LLC), flag after vmcnt-draining barrier.
template <int H, int UNITS, int LANES, int JI, bool PRE_BF16, bool W_PACK_BF16, bool WRITE_H1SEQ>
__global__ __launch_bounds__(256, 1) void lstm_rec_kernel(
        const void* __restrict__ pre_,
        const float* __restrict__ whh,      // f32 [4H, H]
        uint32_t* __restrict__ comm,        // f32 double buffer [2*H]
        ushort_t* __restrict__ h1seq,       // bf16 [T*H] (only if WRITE_H1SEQ)
        int* __restrict__ flags, int T) {
    static_assert(UNITS * LANES == 256, "bad cfg");
    static_assert(LANES * 4 * JI == H, "bad cfg");
    constexpr int WPT = H / 256;

    __shared__ float h_lds[H];

    int tid = threadIdx.x;
    int blk = blockIdx.x;
    int dg  = tid / LANES;
    int ln  = tid % LANES;
    int unit = blk * UNITS + dg;

    // ---- load this thread's weights into registers ----
    uint32_t wp[W_PACK_BF16 ? 4 : 1][W_PACK_BF16 ? JI : 1][2];  // packed bf16 pairs
    float    wf[W_PACK_BF16 ? 1 : 4][W_PACK_BF16 ? 1 : JI][4];  // f32
    #pragma unroll
    for (int g = 0; g < 4; ++g) {
        const float* wr = whh + ((size_t)g * H + unit) * H;
        #pragma unroll
        for (int j = 0; j < JI; ++j) {
            f32x4 v = *(const f32x4*)(wr + ln * 4 + j * (LANES * 4));
            if constexpr (W_PACK_BF16) {
                wp[g][j][0] = (uint32_t)f32_to_bf16(v[0]) | ((uint32_t)f32_to_bf16(v[1]) << 16);
                wp[g][j][1] = (uint32_t)f32_to_bf16(v[2]) | ((uint32_t)f32_to_bf16(v[3]) << 16);
            } else {
                wf[g][j][0] = v[0]; wf[g][j][1] = v[1];
                wf[g][j][2] = v[2]; wf[g][j][3] = v[3];
            }
        }
    }

    float c_reg = 0.0f;   // valid on ln==0

    for (int t = 0; t < T; ++t) {
        // prefetch pre-activations for this step (independent of h[t-1])
        float p[4];
        if (ln == 0) {
            #pragma unroll
            for (int g = 0; g < 4; ++g) {
                size_t idx = (size_t)t * (4 * H) + (size_t)g * H + unit;
                if constexpr (PRE_BF16) p[g] = bf16_val(((const ushort_t*)pre_)[idx]);
                else                    p[g] = ((const float*)pre_)[idx];
            }
        }

        if (t > 0) {
            // wait for all 256 blocks to have published h[t-1]
            while (__hip_atomic_load(&flags[tid], __ATOMIC_RELAXED,
                                     __HIP_MEMORY_SCOPE_AGENT) < t) {
                __builtin_amdgcn_s_sleep(1);
            }
        }
        __syncthreads();

        if (t > 0) {
            // stage h[t-1] into LDS: coalesced LLC loads, conflict-free stride-1 LDS writes
            size_t cb = (size_t)((t - 1) & 1) * H;
            #pragma unroll
            for (int w0 = 0; w0 < WPT; ++w0) {
                int w = tid + w0 * 256;
                uint32_t v = __hip_atomic_load(&comm[cb + w], __ATOMIC_RELAXED,
                                               __HIP_MEMORY_SCOPE_AGENT);
                union { uint32_t u; float f; } x; x.u = v;
                h_lds[w] = x.f;
            }
        }
        __syncthreads();

        float acc[4] = {0.f, 0.f, 0.f, 0.f};
        if (t > 0) {
            #pragma unroll
            for (int j = 0; j < JI; ++j) {
                f32x4 h4 = *(const f32x4*)&h_lds[ln * 4 + j * (LANES * 4)];
                #pragma unroll
                for (int g = 0; g < 4; ++g) {
                    if constexpr (W_PACK_BF16) {
                        uint32_t u0 = wp[g][j][0], u1 = wp[g][j][1];
                        acc[g] = fmaf(bf16_lo(u0), h4[0], acc[g]);
                        acc[g] = fmaf(bf16_hi(u0), h4[1], acc[g]);
                        acc[g] = fmaf(bf16_lo(u1), h4[2], acc[g]);
                        acc[g] = fmaf(bf16_hi(u1), h4[3], acc[g]);
                    } else {
                        acc[g] = fmaf(wf[g][j][0], h4[0], acc[g]);
                        acc[g] = fmaf(wf[g][j][1], h4[1], acc[g]);
                        acc[g] = fmaf(wf[g][j][2], h4[2], acc[g]);
                        acc[g] = fmaf(wf[g][j][3], h4[3], acc[g]);
                    }
                }
            }
        }
        // reduce the 4 gate dots across the LANES group
        #pragma unroll
        for (int off = LANES / 2; off > 0; off >>= 1) {
            #pragma unroll
            for (int g = 0; g < 4; ++g)
                acc[g] += __shfl_down(acc[g], off, LANES);
        }

        if (ln == 0) {
            float iv = sigmoidf(p[0] + acc[0]);
            float fv = sigmoidf(p[1] + acc[1]);
            float gv = tanhf  (p[2] + acc[2]);
            float ov = sigmoidf(p[3] + acc[3]);
            c_reg = fv * c_reg + iv * gv;
            float h = ov * tanhf(c_reg);
            union { float f; uint32_t u; } x; x.f = h;
            __hip_atomic_store(&comm[(size_t)(t & 1) * H + unit], x.u,
                               __ATOMIC_RELAXED, __HIP_MEMORY_SCOPE_AGENT);
            if constexpr (WRITE_H1SEQ)
                h1seq[(size_t)t * H + unit] = f32_to_bf16(h);
        }
        // barrier drains vmcnt for every thread -> all h stores are at LLC before flag store
        __syncthreads();
        if (tid == 0)
            __hip_atomic_store(&flags[blk], t + 1, __ATOMIC_RELAXED,
                               __HIP_MEMORY_SCOPE_AGENT);
    }
}

// ---------------- small matvec: out[j] = W[j,:K] . x + bias[j], one wave per output ----------------
__global__ __launch_bounds__(256) void linear_vec_kernel(const float* __restrict__ W,
                                                         const float* __restrict__ bias,
                                                         const float* __restrict__ x,
                                                         float* __restrict__ out,
                                                         int N, int K) {
    int wave = threadIdx.x >> 6;
    int lane = threadIdx.x & 63;
    int j = blockIdx.x * 4 + wave;
    if (j >= N) return;
    const float* wr = W + (size_t)j * K;
    float s = 0.0f;
    for (int k = lane; k < K; k += 64) s += wr[k] * x[k];
    #pragma unroll
    for (int off = 32; off > 0; off >>= 1) s += __shfl_down(s, off, 64);
    if (lane == 0) out[j] = s + bias[j];
}

extern "C" void kernel_launch(void* const* d_in, const int* in_sizes, int n_in,
                              void* d_out, int out_size, void* d_ws, size_t ws_size,
                              hipStream_t stream) {
    const float* x_f    = (const float*)d_in[0];
    const float* wih1_f = (const float*)d_in[1];
    const float* whh1_f = (const float*)d_in[2];
    const float* bih1   = (const float*)d_in[3];
    const float* bhh1   = (const float*)d_in[4];
    const float* wih2_f = (const float*)d_in[5];
    const float* whh2_f = (const float*)d_in[6];
    const float* bih2   = (const float*)d_in[7];
    const float* bhh2   = (const float*)d_in[8];
    const float* wl1    = (const float*)d_in[9];
    const float* bl1    = (const float*)d_in[10];
    const float* wl2    = (const float*)d_in[11];
    const float* bl2    = (const float*)d_in[12];

    uint8_t* base = (uint8_t*)d_ws;
    size_t off = 0;
    auto alloc = [&](size_t bytes) { size_t o = off; off = (off + bytes + 255) & ~(size_t)255; return o; };

    size_t pre1_off  = alloc((size_t)T_SEQ * G1 * 4);   // f32 [T,4096]
    size_t pre2_off  = alloc((size_t)T_SEQ * G2 * 2);   // bf16 [T,8192]
    size_t h1seq_off = alloc((size_t)T_SEQ * H1 * 2);   // bf16 [T,1024]
    size_t wih1_off  = alloc((size_t)G1 * IN_SZ * 2);
    size_t wih2_off  = alloc((size_t)G2 * H1 * 2);
    size_t xb_off    = alloc((size_t)T_SEQ * IN_SZ * 2);
    size_t comm1_off = alloc((size_t)2 * H1 * 4);       // f32 double buffer
    size_t comm2_off = alloc((size_t)2 * H2 * 4);       // f32 double buffer
    size_t p1_off    = alloc((size_t)L1OUT * 4);
    size_t flags_off = alloc((size_t)512 * 4);          // flags1[256] ++ flags2[256]

    float*    pre1  = (float*)(base + pre1_off);
    ushort_t* pre2  = (ushort_t*)(base + pre2_off);
    ushort_t* h1seq = (ushort_t*)(base + h1seq_off);
    ushort_t* wih1b = (ushort_t*)(base + wih1_off);
    ushort_t* wih2b = (ushort_t*)(base + wih2_off);
    ushort_t* xb    = (ushort_t*)(base + xb_off);
    uint32_t* comm1 = (uint32_t*)(base + comm1_off);
    uint32_t* comm2 = (uint32_t*)(base + comm2_off);
    float*    p1    = (float*)(base + p1_off);
    int*      flags1 = (int*)(base + flags_off);
    int*      flags2 = flags1 + 256;

    // zero the sync flags (ws is poisoned 0xAA before every launch)
    hipMemsetAsync(flags1, 0, 512 * sizeof(int), stream);

    // f32 -> bf16 conversions (GEMM inputs only; recurrence reads f32 weights directly)
    cvt_bf16_kernel<<<2048, 256, 0, stream>>>(x_f,    xb,    T_SEQ * IN_SZ);
    cvt_bf16_kernel<<<2048, 256, 0, stream>>>(wih1_f, wih1b, G1 * IN_SZ);
    cvt_bf16_kernel<<<2048, 256, 0, stream>>>(wih2_f, wih2b, G2 * H1);

    // pre1 = x @ wih1^T + (bih1 + bhh1)   [f32 out]
    {
        dim3 grid(G1 / 64, T_SEQ / 64);
        gemm_bt_kernel<false><<<grid, 256, 0, stream>>>(xb, wih1b, pre1, (ushort_t*)nullptr,
                                                        bih1, bhh1, T_SEQ, G1, IN_SZ);
    }
    // layer-1 recurrence: H=1024, 4 units/block, 64 lanes/unit, JI=4, f32 weights in regs
    lstm_rec_kernel<H1, 4, 64, 4, false, false, true><<<256, 256, 0, stream>>>(
        pre1, whh1_f, comm1, h1seq, flags1, T_SEQ);

    // pre2 = h1 @ wih2^T + (bih2 + bhh2)  [bf16 out]
    {
        dim3 grid(G2 / 64, T_SEQ / 64);
        gemm_bt_kernel<true><<<grid, 256, 0, stream>>>(h1seq, wih2b, (float*)nullptr, pre2,
                                                       bih2, bhh2, T_SEQ, G2, H1);
    }
    // layer-2 recurrence: H=2048, 8 units/block, 32 lanes/unit, JI=16, packed-bf16 weights in regs
    lstm_rec_kernel<H2, 8, 32, 16, true, true, false><<<256, 256, 0, stream>>>(
        pre2, whh2_f, comm2, (ushort_t*)nullptr, flags2, T_SEQ);

    // final h2 lives at parity (T-1)&1 == 1
    linear_vec_kernel<<<L1OUT / 4, 256, 0, stream>>>(wl1, bl1, (float*)(comm2 + H2), p1, L1OUT, H2);
    linear_vec_kernel<<<OUT_SZ / 4, 256, 0, stream>>>(wl2, bl2, p1, (float*)d_out, OUT_SZ, L1OUT);

    (void)in_sizes; (void)n_in; (void)out_size; (void)ws_size;
}

// Round 3
// 38647.028 us; speedup vs baseline: 1.8061x; 1.2133x over previous
//
#include <hip/hip_runtime.h>
#include <stdint.h>

typedef unsigned short ushort_t;
typedef __attribute__((ext_vector_type(8))) short short8;
typedef __attribute__((ext_vector_type(4))) float f32x4;

#define T_SEQ 4096
#define IN_SZ 512
#define H1 1024
#define H2 2048
#define G1 (4*H1)   // 4096
#define G2 (4*H2)   // 8192
#define OUT_SZ 512
#define L1OUT 1024

#define SENT 0xAAAAAAAAu

__device__ __forceinline__ ushort_t f32_to_bf16(float f) {
    union { float f; uint32_t u; } x; x.f = f;
    uint32_t u = x.u;
    uint32_t r = (u + 0x7fffu + ((u >> 16) & 1u)) >> 16;
    return (ushort_t)r;
}
__device__ __forceinline__ float bf16_lo(uint32_t p) {
    union { uint32_t u; float f; } x; x.u = p << 16; return x.f;
}
__device__ __forceinline__ float bf16_hi(uint32_t p) {
    union { uint32_t u; float f; } x; x.u = p & 0xffff0000u; return x.f;
}
__device__ __forceinline__ float bf16_val(ushort_t v) {
    union { uint32_t u; float f; } x; x.u = ((uint32_t)v) << 16; return x.f;
}
__device__ __forceinline__ float sigmoidf(float x) {
    return 1.0f / (1.0f + expf(-x));
}

// ---------------- f32 -> bf16 conversion ----------------
__global__ __launch_bounds__(256) void cvt_bf16_kernel(const float* __restrict__ in,
                                                       ushort_t* __restrict__ out, int n) {
    int i = blockIdx.x * 256 + threadIdx.x;
    int stride = gridDim.x * 256;
    for (; i < n; i += stride) out[i] = f32_to_bf16(in[i]);
}

// ---------------- bf16 MFMA GEMM: C[M,N] = A[M,K] * B[N,K]^T + bias_a[n] + bias_b[n] ----------------
template <bool OUT_BF16>
__global__ __launch_bounds__(256) void gemm_bt_kernel(const ushort_t* __restrict__ A,
                                                      const ushort_t* __restrict__ B,
                                                      float* __restrict__ Cf,
                                                      ushort_t* __restrict__ Cb,
                                                      const float* __restrict__ bias_a,
                                                      const float* __restrict__ bias_b,
                                                      int M, int N, int K) {
    int tid  = threadIdx.x;
    int wave = tid >> 6;
    int lane = tid & 63;
    int l15  = lane & 15;
    int quad = lane >> 4;
    int m0 = blockIdx.y * 64 + wave * 16;
    int n0 = blockIdx.x * 64;

    const ushort_t* pa = A + (size_t)(m0 + l15) * K + quad * 8;
    f32x4 acc[4];
    #pragma unroll
    for (int i = 0; i < 4; ++i) acc[i] = (f32x4){0.f, 0.f, 0.f, 0.f};

    for (int kc = 0; kc < K; kc += 32) {
        short8 a = *(const short8*)(pa + kc);
        #pragma unroll
        for (int nf = 0; nf < 4; ++nf) {
            const ushort_t* pb = B + (size_t)(n0 + nf * 16 + l15) * K + quad * 8 + kc;
            short8 b = *(const short8*)pb;
            acc[nf] = __builtin_amdgcn_mfma_f32_16x16x32_bf16(a, b, acc[nf], 0, 0, 0);
        }
    }

    int rbase = quad * 4;
    #pragma unroll
    for (int nf = 0; nf < 4; ++nf) {
        int n = n0 + nf * 16 + l15;
        float bb = bias_a[n] + bias_b[n];
        #pragma unroll
        for (int r = 0; r < 4; ++r) {
            int m = m0 + rbase + r;
            float v = acc[nf][r] + bb;
            if (OUT_BF16) Cb[(size_t)m * N + n] = f32_to_bf16(v);
            else          Cf[(size_t)m * N + n] = v;
        }
    }
}

// ---------------- Persistent LSTM recurrence: LDS-resident bf16 weights + sentinel data-polling ----
// Grid = NB blocks x 256 threads (1 block/CU). Block owns UNITS units; thread (dg,ln) covers all
// 4 gates of unit (blk*UNITS+dg) over k-chunks {ln*8 + j*LANES*8}. Weights staged to LDS once.
// comm is PER-STEP: consumers poll words against the 0xAA sentinel (data IS the signal; no flags).
// PACK_OUT: comm[t][H/2] u32 = packed bf16 pairs (doubles as h1seq for the next GEMM);
// else comm[t][H] f32 words.
template <int H, int UNITS, int LANES, bool PACK_OUT>
__global__ __launch_bounds__(256, 1) void lstm_rec_kernel(
        const ushort_t* __restrict__ pre_,   // bf16 [T, 4H]
        const ushort_t* __restrict__ whhb,   // bf16 [4H, H]
        uint32_t* __restrict__ comm,         // per-step words, pre-poisoned 0xAA
        int T) {
    static_assert(UNITS * LANES == 256, "bad cfg");
    constexpr int WORDS = PACK_OUT ? H / 2 : H;
    constexpr int WPT   = WORDS / 256;
    constexpr int J     = H / (LANES * 8);

    extern __shared__ char smem[];
    ushort_t* w_lds = (ushort_t*)smem;                       // [4*UNITS][H] bf16
    float*    h_lds = (float*)(smem + (size_t)4 * UNITS * H * 2);  // [H]
    float*    h_own = h_lds + H;                             // [UNITS]

    int tid = threadIdx.x;
    int blk = blockIdx.x;
    int dg  = tid / LANES;   // local unit
    int ln  = tid % LANES;
    int unit = blk * UNITS + dg;

    // ---- stage this block's weight slice into LDS (each thread copies what it will read) ----
    #pragma unroll
    for (int g = 0; g < 4; ++g) {
        const ushort_t* wr = whhb + ((size_t)g * H + unit) * H;
        #pragma unroll
        for (int j = 0; j < J; ++j) {
            int k = ln * 8 + j * (LANES * 8);
            *(short8*)(w_lds + (size_t)(dg * 4 + g) * H + k) = *(const short8*)(wr + k);
        }
    }

    float c_reg = 0.0f;   // valid on ln==0

    for (int t = 0; t < T; ++t) {
        // prefetch pre-activations (independent of h[t-1])
        float p[4];
        if (ln == 0) {
            #pragma unroll
            for (int g = 0; g < 4; ++g)
                p[g] = bf16_val(pre_[(size_t)t * (4 * H) + (size_t)g * H + unit]);
        }

        if (t > 0) {
            // sentinel-poll h[t-1] words and stage into LDS (coalesced; data is the signal)
            const uint32_t* src = comm + (size_t)(t - 1) * WORDS;
            #pragma unroll
            for (int w0 = 0; w0 < WPT; ++w0) {
                int w = tid + w0 * 256;
                uint32_t v;
                for (;;) {
                    v = __hip_atomic_load(&src[w], __ATOMIC_RELAXED, __HIP_MEMORY_SCOPE_AGENT);
                    if (v != SENT) break;
                    __builtin_amdgcn_s_sleep(1);
                }
                if (PACK_OUT) {
                    h_lds[2 * w]     = bf16_lo(v);
                    h_lds[2 * w + 1] = bf16_hi(v);
                } else {
                    union { uint32_t u; float f; } x; x.u = v;
                    h_lds[w] = x.f;
                }
            }
        }
        __syncthreads();   // h_lds ready (and prior-step h_lds readers done before next overwrite)

        float acc[4] = {0.f, 0.f, 0.f, 0.f};
        if (t > 0) {
            #pragma unroll
            for (int j = 0; j < J; ++j) {
                int k = ln * 8 + j * (LANES * 8);
                f32x4 hA = *(const f32x4*)&h_lds[k];
                f32x4 hB = *(const f32x4*)&h_lds[k + 4];
                #pragma unroll
                for (int g = 0; g < 4; ++g) {
                    uint4 wv = *(const uint4*)(w_lds + (size_t)(dg * 4 + g) * H + k);
                    acc[g] = fmaf(bf16_lo(wv.x), hA[0], acc[g]);
                    acc[g] = fmaf(bf16_hi(wv.x), hA[1], acc[g]);
                    acc[g] = fmaf(bf16_lo(wv.y), hA[2], acc[g]);
                    acc[g] = fmaf(bf16_hi(wv.y), hA[3], acc[g]);
                    acc[g] = fmaf(bf16_lo(wv.z), hB[0], acc[g]);
                    acc[g] = fmaf(bf16_hi(wv.z), hB[1], acc[g]);
                    acc[g] = fmaf(bf16_lo(wv.w), hB[2], acc[g]);
                    acc[g] = fmaf(bf16_hi(wv.w), hB[3], acc[g]);
                }
            }
        }
        // reduce within the LANES group
        #pragma unroll
        for (int off = LANES / 2; off > 0; off >>= 1) {
            #pragma unroll
            for (int g = 0; g < 4; ++g)
                acc[g] += __shfl_down(acc[g], off, LANES);
        }

        if (ln == 0) {
            float iv = sigmoidf(p[0] + acc[0]);
            float fv = sigmoidf(p[1] + acc[1]);
            float gv = tanhf  (p[2] + acc[2]);
            float ov = sigmoidf(p[3] + acc[3]);
            c_reg = fv * c_reg + iv * gv;
            float h = ov * tanhf(c_reg);
            if (PACK_OUT) {
                h_own[dg] = h;
            } else {
                union { float f; uint32_t u; } x; x.f = h;
                __hip_atomic_store(&comm[(size_t)t * WORDS + unit], x.u,
                                   __ATOMIC_RELAXED, __HIP_MEMORY_SCOPE_AGENT);
            }
        }
        if (PACK_OUT) {
            __syncthreads();   // h_own ready; also protects h_lds from next-step staging
            if (tid < UNITS / 2) {
                uint32_t lo = f32_to_bf16(h_own[2 * tid]);
                uint32_t hi = f32_to_bf16(h_own[2 * tid + 1]);
                __hip_atomic_store(&comm[(size_t)t * WORDS + blk * (UNITS / 2) + tid],
                                   lo | (hi << 16),
                                   __ATOMIC_RELAXED, __HIP_MEMORY_SCOPE_AGENT);
            }
        } else {
            __syncthreads();   // protect h_lds: all compute reads done before next-step staging
        }
        // no trailing flag: consumers poll the data itself
    }
}

// ---------------- small matvec: out[j] = W[j,:K] . x + bias[j], one wave per output ----------------
__global__ __launch_bounds__(256) void linear_vec_kernel(const float* __restrict__ W,
                                                         const float* __restrict__ bias,
                                                         const float* __restrict__ x,
                                                         float* __restrict__ out,
                                                         int N, int K) {
    int wave = threadIdx.x >> 6;
    int lane = threadIdx.x & 63;
    int j = blockIdx.x * 4 + wave;
    if (j >= N) return;
    const float* wr = W + (size_t)j * K;
    float s = 0.0f;
    for (int k = lane; k < K; k += 64) s += wr[k] * x[k];
    #pragma unroll
    for (int off = 32; off > 0; off >>= 1) s += __shfl_down(s, off, 64);
    if (lane == 0) out[j] = s + bias[j];
}

extern "C" void kernel_launch(void* const* d_in, const int* in_sizes, int n_in,
                              void* d_out, int out_size, void* d_ws, size_t ws_size,
                              hipStream_t stream) {
    const float* x_f    = (const float*)d_in[0];
    const float* wih1_f = (const float*)d_in[1];
    const float* whh1_f = (const float*)d_in[2];
    const float* bih1   = (const float*)d_in[3];
    const float* bhh1   = (const float*)d_in[4];
    const float* wih2_f = (const float*)d_in[5];
    const float* whh2_f = (const float*)d_in[6];
    const float* bih2   = (const float*)d_in[7];
    const float* bhh2   = (const float*)d_in[8];
    const float* wl1    = (const float*)d_in[9];
    const float* bl1    = (const float*)d_in[10];
    const float* wl2    = (const float*)d_in[11];
    const float* bl2    = (const float*)d_in[12];

    uint8_t* base = (uint8_t*)d_ws;
    size_t off = 0;
    auto alloc = [&](size_t bytes) { size_t o = off; off = (off + bytes + 255) & ~(size_t)255; return o; };

    size_t pre1_off  = alloc((size_t)T_SEQ * G1 * 2);   // bf16 [T,4096]
    size_t pre2_off  = alloc((size_t)T_SEQ * G2 * 2);   // bf16 [T,8192]
    size_t comm1_off = alloc((size_t)T_SEQ * (H1/2) * 4); // u32 packed bf16 [T,512] == h1seq
    size_t comm2_off = alloc((size_t)T_SEQ * H2 * 4);   // f32 [T,2048]
    size_t whh1_off  = alloc((size_t)G1 * H1 * 2);
    size_t whh2_off  = alloc((size_t)G2 * H2 * 2);
    size_t wih1_off  = alloc((size_t)G1 * IN_SZ * 2);
    size_t wih2_off  = alloc((size_t)G2 * H1 * 2);
    size_t xb_off    = alloc((size_t)T_SEQ * IN_SZ * 2);
    size_t p1_off    = alloc((size_t)L1OUT * 4);

    ushort_t* pre1  = (ushort_t*)(base + pre1_off);
    ushort_t* pre2  = (ushort_t*)(base + pre2_off);
    uint32_t* comm1 = (uint32_t*)(base + comm1_off);
    uint32_t* comm2 = (uint32_t*)(base + comm2_off);
    ushort_t* whh1b = (ushort_t*)(base + whh1_off);
    ushort_t* whh2b = (ushort_t*)(base + whh2_off);
    ushort_t* wih1b = (ushort_t*)(base + wih1_off);
    ushort_t* wih2b = (ushort_t*)(base + wih2_off);
    ushort_t* xb    = (ushort_t*)(base + xb_off);
    float*    p1    = (float*)(base + p1_off);

    // poison the sentinel comm buffers ourselves (don't rely on harness poison for the
    // un-timed correctness call)
    hipMemsetAsync(comm1, 0xAA, (size_t)T_SEQ * (H1/2) * 4, stream);
    hipMemsetAsync(comm2, 0xAA, (size_t)T_SEQ * H2 * 4, stream);

    // f32 -> bf16 conversions
    cvt_bf16_kernel<<<2048, 256, 0, stream>>>(x_f,    xb,    T_SEQ * IN_SZ);
    cvt_bf16_kernel<<<2048, 256, 0, stream>>>(wih1_f, wih1b, G1 * IN_SZ);
    cvt_bf16_kernel<<<2048, 256, 0, stream>>>(whh1_f, whh1b, G1 * H1);
    cvt_bf16_kernel<<<2048, 256, 0, stream>>>(wih2_f, wih2b, G2 * H1);
    cvt_bf16_kernel<<<4096, 256, 0, stream>>>(whh2_f, whh2b, G2 * H2);

    // pre1 = x @ wih1^T + (bih1 + bhh1)   [bf16 out]
    {
        dim3 grid(G1 / 64, T_SEQ / 64);
        gemm_bt_kernel<true><<<grid, 256, 0, stream>>>(xb, wih1b, (float*)nullptr, pre1,
                                                       bih1, bhh1, T_SEQ, G1, IN_SZ);
    }
    // layer-1 recurrence: 128 blocks, 8 units/block, LDS = 64KB weights + 4KB h
    {
        size_t shmem = (size_t)4 * 8 * H1 * 2 + H1 * 4 + 8 * 4 + 64;
        lstm_rec_kernel<H1, 8, 32, true><<<128, 256, shmem, stream>>>(
            pre1, whh1b, comm1, T_SEQ);
    }
    // pre2 = h1 @ wih2^T + (bih2 + bhh2)  [bf16 out]; comm1 IS row-major bf16 [T,H1]
    {
        dim3 grid(G2 / 64, T_SEQ / 64);
        gemm_bt_kernel<true><<<grid, 256, 0, stream>>>((const ushort_t*)comm1, wih2b,
                                                       (float*)nullptr, pre2,
                                                       bih2, bhh2, T_SEQ, G2, H1);
    }
    // layer-2 recurrence: 256 blocks, 8 units/block, LDS = 128KB weights + 8KB h
    {
        size_t shmem = (size_t)4 * 8 * H2 * 2 + H2 * 4 + 8 * 4 + 64;
        lstm_rec_kernel<H2, 8, 32, false><<<256, 256, shmem, stream>>>(
            pre2, whh2b, comm2, T_SEQ);
    }

    // p1 = wl1 . h2[T-1] + bl1 ; out = wl2 . p1 + bl2
    const float* h2_last = (const float*)(comm2 + (size_t)(T_SEQ - 1) * H2);
    linear_vec_kernel<<<L1OUT / 4, 256, 0, stream>>>(wl1, bl1, h2_last, p1, L1OUT, H2);
    linear_vec_kernel<<<OUT_SZ / 4, 256, 0, stream>>>(wl2, bl2, p1, (float*)d_out, OUT_SZ, L1OUT);

    (void)in_sizes; (void)n_in; (void)out_size; (void)ws_size;
}

// Round 4
// 34816.776 us; speedup vs baseline: 2.0048x; 1.1100x over previous
//
#include <hip/hip_runtime.h>
#include <stdint.h>

typedef unsigned short ushort_t;
typedef __attribute__((ext_vector_type(8))) short short8;
typedef __attribute__((ext_vector_type(4))) float f32x4;

#define T_SEQ 4096
#define IN_SZ 512
#define H1 1024
#define H2 2048
#define G1 (4*H1)   // 4096
#define G2 (4*H2)   // 8192
#define OUT_SZ 512
#define L1OUT 1024

#define SENT 0xAAAAAAAAu

__device__ __forceinline__ ushort_t f32_to_bf16(float f) {
    union { float f; uint32_t u; } x; x.f = f;
    uint32_t u = x.u;
    uint32_t r = (u + 0x7fffu + ((u >> 16) & 1u)) >> 16;
    return (ushort_t)r;
}
__device__ __forceinline__ float bf16_lo(uint32_t p) {
    union { uint32_t u; float f; } x; x.u = p << 16; return x.f;
}
__device__ __forceinline__ float bf16_hi(uint32_t p) {
    union { uint32_t u; float f; } x; x.u = p & 0xffff0000u; return x.f;
}
__device__ __forceinline__ float bf16_val(ushort_t v) {
    union { uint32_t u; float f; } x; x.u = ((uint32_t)v) << 16; return x.f;
}
__device__ __forceinline__ float sigmoidf(float x) {
    return 1.0f / (1.0f + expf(-x));
}

// ---------------- f32 -> bf16 conversion ----------------
__global__ __launch_bounds__(256) void cvt_bf16_kernel(const float* __restrict__ in,
                                                       ushort_t* __restrict__ out, int n) {
    int i = blockIdx.x * 256 + threadIdx.x;
    int stride = gridDim.x * 256;
    for (; i < n; i += stride) out[i] = f32_to_bf16(in[i]);
}

// ---------------- bf16 MFMA GEMM: C[M,N] = A[M,K] * B[N,K]^T + bias_a[n] + bias_b[n] ----------------
template <bool OUT_BF16>
__global__ __launch_bounds__(256) void gemm_bt_kernel(const ushort_t* __restrict__ A,
                                                      const ushort_t* __restrict__ B,
                                                      float* __restrict__ Cf,
                                                      ushort_t* __restrict__ Cb,
                                                      const float* __restrict__ bias_a,
                                                      const float* __restrict__ bias_b,
                                                      int M, int N, int K) {
    int tid  = threadIdx.x;
    int wave = tid >> 6;
    int lane = tid & 63;
    int l15  = lane & 15;
    int quad = lane >> 4;
    int m0 = blockIdx.y * 64 + wave * 16;
    int n0 = blockIdx.x * 64;

    const ushort_t* pa = A + (size_t)(m0 + l15) * K + quad * 8;
    f32x4 acc[4];
    #pragma unroll
    for (int i = 0; i < 4; ++i) acc[i] = (f32x4){0.f, 0.f, 0.f, 0.f};

    for (int kc = 0; kc < K; kc += 32) {
        short8 a = *(const short8*)(pa + kc);
        #pragma unroll
        for (int nf = 0; nf < 4; ++nf) {
            const ushort_t* pb = B + (size_t)(n0 + nf * 16 + l15) * K + quad * 8 + kc;
            short8 b = *(const short8*)pb;
            acc[nf] = __builtin_amdgcn_mfma_f32_16x16x32_bf16(a, b, acc[nf], 0, 0, 0);
        }
    }

    int rbase = quad * 4;
    #pragma unroll
    for (int nf = 0; nf < 4; ++nf) {
        int n = n0 + nf * 16 + l15;
        float bb = bias_a[n] + bias_b[n];
        #pragma unroll
        for (int r = 0; r < 4; ++r) {
            int m = m0 + rbase + r;
            float v = acc[nf][r] + bb;
            if (OUT_BF16) Cb[(size_t)m * N + n] = f32_to_bf16(v);
            else          Cf[(size_t)m * N + n] = v;
        }
    }
}

// ---------------- Persistent LSTM recurrence ----------------
// NB blocks x 256 threads (1 block/CU). Block owns UNITS units; thread (dg,ln) computes all
// 4 gates of unit (blk*UNITS+dg) over 8-float k-chunks {ln*8 + j*LANES*8}. bf16 weights in LDS.
// Sentinel data-polling on per-step comm (data IS the signal; no flags). Polls are BATCH-ISSUED
// (all WPT loads per round -> 1 LLC round-trip, not WPT). h staged in LDS de-interleaved into
// even/odd 4-float arrays (all LDS reads lane-contiguous 16B), parity double-buffered so the
// step needs only ONE barrier. Producer publish: packed bf16 pair via cross-lane shfl (PACK_OUT)
// or one f32 word per unit.
template <int H, int UNITS, int LANES, bool PACK_OUT>
__global__ __launch_bounds__(256, 1) void lstm_rec_kernel(
        const ushort_t* __restrict__ pre_,   // bf16 [T, 4H]
        const ushort_t* __restrict__ whhb,   // bf16 [4H, H]
        uint32_t* __restrict__ comm,         // per-step words, pre-poisoned 0xAA
        int T) {
    static_assert(UNITS * LANES == 256, "bad cfg");
    constexpr int WORDS = PACK_OUT ? H / 2 : H;
    constexpr int WPT   = WORDS / 256;
    constexpr int J     = H / (LANES * 8);

    extern __shared__ char smem[];
    ushort_t* w_lds = (ushort_t*)smem;                         // [4*UNITS][H] bf16
    float*    hb    = (float*)(smem + (size_t)4 * UNITS * H * 2); // [2 parity][2 arr][H/2]

    int tid = threadIdx.x;
    int blk = blockIdx.x;
    int dg  = tid / LANES;   // local unit
    int ln  = tid % LANES;
    int unit = blk * UNITS + dg;

    // ---- stage this block's weight slice into LDS (coalesced, each thread copies what it reads) ----
    #pragma unroll
    for (int g = 0; g < 4; ++g) {
        const ushort_t* wr = whhb + ((size_t)g * H + unit) * H;
        #pragma unroll
        for (int j = 0; j < J; ++j) {
            int k = ln * 8 + j * (LANES * 8);
            *(short8*)(w_lds + (size_t)(dg * 4 + g) * H + k) = *(const short8*)(wr + k);
        }
    }

    float c_reg = 0.0f;   // valid on ln==0

    for (int t = 0; t < T; ++t) {
        // prefetch pre-activations early (HBM latency hidden behind the poll)
        float p[4];
        if (ln == 0) {
            #pragma unroll
            for (int g = 0; g < 4; ++g)
                p[g] = bf16_val(pre_[(size_t)t * (4 * H) + (size_t)g * H + unit]);
        }

        if (t > 0) {
            // ---- batch-issued sentinel poll: all WPT loads in flight per round ----
            const uint32_t* src = comm + (size_t)(t - 1) * WORDS;
            uint32_t v[WPT];
            for (;;) {
                #pragma unroll
                for (int w0 = 0; w0 < WPT; ++w0)
                    v[w0] = __hip_atomic_load(&src[tid + w0 * 256], __ATOMIC_RELAXED,
                                              __HIP_MEMORY_SCOPE_AGENT);
                bool bad = false;
                #pragma unroll
                for (int w0 = 0; w0 < WPT; ++w0) bad |= (v[w0] == SENT);
                if (!bad) break;
                __builtin_amdgcn_s_sleep(1);
            }
            // ---- de-interleaved stage into parity buffer ----
            float* hA = hb + ((t - 1) & 1) * H;
            float* hB = hA + (H / 2);
            #pragma unroll
            for (int w0 = 0; w0 < WPT; ++w0) {
                int w = tid + w0 * 256;
                if (PACK_OUT) {
                    // word w = elements 2w, 2w+1
                    int arr = (w >> 1) & 1;
                    int idx = ((w >> 2) << 2) + 2 * (w & 1);
                    float* dst = arr ? hB : hA;
                    dst[idx]     = bf16_lo(v[w0]);
                    dst[idx + 1] = bf16_hi(v[w0]);
                } else {
                    // word w = element w
                    int arr = (w >> 2) & 1;
                    int idx = ((w >> 3) << 2) + (w & 3);
                    union { uint32_t u; float f; } x; x.u = v[w0];
                    (arr ? hB : hA)[idx] = x.f;
                }
            }
        }
        __syncthreads();   // the ONLY barrier per step (parity buffers handle WAR across steps)

        float acc[4] = {0.f, 0.f, 0.f, 0.f};
        if (t > 0) {
            const float* hA = hb + ((t - 1) & 1) * H;
            const float* hB = hA + (H / 2);
            #pragma unroll
            for (int j = 0; j < J; ++j) {
                int k4 = ln * 4 + j * (LANES * 4);
                f32x4 a = *(const f32x4*)&hA[k4];   // elements k..k+3
                f32x4 b = *(const f32x4*)&hB[k4];   // elements k+4..k+7
                #pragma unroll
                for (int g = 0; g < 4; ++g) {
                    uint4 wv = *(const uint4*)(w_lds + (size_t)(dg * 4 + g) * H
                                               + ln * 8 + j * (LANES * 8));
                    acc[g] = fmaf(bf16_lo(wv.x), a[0], acc[g]);
                    acc[g] = fmaf(bf16_hi(wv.x), a[1], acc[g]);
                    acc[g] = fmaf(bf16_lo(wv.y), a[2], acc[g]);
                    acc[g] = fmaf(bf16_hi(wv.y), a[3], acc[g]);
                    acc[g] = fmaf(bf16_lo(wv.z), b[0], acc[g]);
                    acc[g] = fmaf(bf16_hi(wv.z), b[1], acc[g]);
                    acc[g] = fmaf(bf16_lo(wv.w), b[2], acc[g]);
                    acc[g] = fmaf(bf16_hi(wv.w), b[3], acc[g]);
                }
            }
        }
        // reduce within the LANES group
        #pragma unroll
        for (int off = LANES / 2; off > 0; off >>= 1) {
            #pragma unroll
            for (int g = 0; g < 4; ++g)
                acc[g] += __shfl_down(acc[g], off, LANES);
        }

        float hval = 0.0f;
        if (ln == 0) {
            float iv = sigmoidf(p[0] + acc[0]);
            float fv = sigmoidf(p[1] + acc[1]);
            float gv = tanhf  (p[2] + acc[2]);
            float ov = sigmoidf(p[3] + acc[3]);
            c_reg = fv * c_reg + iv * gv;
            hval = ov * tanhf(c_reg);
        }
        if (PACK_OUT) {
            // partner unit's h lives LANES lanes away in the same wave
            float hpart = __shfl_down(hval, LANES, 64);
            if (ln == 0 && !(dg & 1)) {
                uint32_t word = (uint32_t)f32_to_bf16(hval)
                              | ((uint32_t)f32_to_bf16(hpart) << 16);
                __hip_atomic_store(&comm[(size_t)t * WORDS + blk * (UNITS / 2) + (dg >> 1)],
                                   word, __ATOMIC_RELAXED, __HIP_MEMORY_SCOPE_AGENT);
            }
        } else {
            if (ln == 0) {
                union { float f; uint32_t u; } x; x.f = hval;
                __hip_atomic_store(&comm[(size_t)t * WORDS + unit], x.u,
                                   __ATOMIC_RELAXED, __HIP_MEMORY_SCOPE_AGENT);
            }
        }
        // no trailing barrier: consumers poll the data itself; parity buffers prevent WAR
    }
}

// ---------------- small matvec: out[j] = W[j,:K] . x + bias[j], one wave per output ----------------
__global__ __launch_bounds__(256) void linear_vec_kernel(const float* __restrict__ W,
                                                         const float* __restrict__ bias,
                                                         const float* __restrict__ x,
                                                         float* __restrict__ out,
                                                         int N, int K) {
    int wave = threadIdx.x >> 6;
    int lane = threadIdx.x & 63;
    int j = blockIdx.x * 4 + wave;
    if (j >= N) return;
    const float* wr = W + (size_t)j * K;
    float s = 0.0f;
    for (int k = lane; k < K; k += 64) s += wr[k] * x[k];
    #pragma unroll
    for (int off = 32; off > 0; off >>= 1) s += __shfl_down(s, off, 64);
    if (lane == 0) out[j] = s + bias[j];
}

extern "C" void kernel_launch(void* const* d_in, const int* in_sizes, int n_in,
                              void* d_out, int out_size, void* d_ws, size_t ws_size,
                              hipStream_t stream) {
    const float* x_f    = (const float*)d_in[0];
    const float* wih1_f = (const float*)d_in[1];
    const float* whh1_f = (const float*)d_in[2];
    const float* bih1   = (const float*)d_in[3];
    const float* bhh1   = (const float*)d_in[4];
    const float* wih2_f = (const float*)d_in[5];
    const float* whh2_f = (const float*)d_in[6];
    const float* bih2   = (const float*)d_in[7];
    const float* bhh2   = (const float*)d_in[8];
    const float* wl1    = (const float*)d_in[9];
    const float* bl1    = (const float*)d_in[10];
    const float* wl2    = (const float*)d_in[11];
    const float* bl2    = (const float*)d_in[12];

    uint8_t* base = (uint8_t*)d_ws;
    size_t off = 0;
    auto alloc = [&](size_t bytes) { size_t o = off; off = (off + bytes + 255) & ~(size_t)255; return o; };

    size_t pre1_off  = alloc((size_t)T_SEQ * G1 * 2);     // bf16 [T,4096]
    size_t pre2_off  = alloc((size_t)T_SEQ * G2 * 2);     // bf16 [T,8192]
    size_t comm1_off = alloc((size_t)T_SEQ * (H1/2) * 4); // u32 packed bf16 [T,512] == h1seq
    size_t comm2_off = alloc((size_t)T_SEQ * H2 * 4);     // f32 [T,2048]
    size_t whh1_off  = alloc((size_t)G1 * H1 * 2);
    size_t whh2_off  = alloc((size_t)G2 * H2 * 2);
    size_t wih1_off  = alloc((size_t)G1 * IN_SZ * 2);
    size_t wih2_off  = alloc((size_t)G2 * H1 * 2);
    size_t xb_off    = alloc((size_t)T_SEQ * IN_SZ * 2);
    size_t p1_off    = alloc((size_t)L1OUT * 4);

    ushort_t* pre1  = (ushort_t*)(base + pre1_off);
    ushort_t* pre2  = (ushort_t*)(base + pre2_off);
    uint32_t* comm1 = (uint32_t*)(base + comm1_off);
    uint32_t* comm2 = (uint32_t*)(base + comm2_off);
    ushort_t* whh1b = (ushort_t*)(base + whh1_off);
    ushort_t* whh2b = (ushort_t*)(base + whh2_off);
    ushort_t* wih1b = (ushort_t*)(base + wih1_off);
    ushort_t* wih2b = (ushort_t*)(base + wih2_off);
    ushort_t* xb    = (ushort_t*)(base + xb_off);
    float*    p1    = (float*)(base + p1_off);

    // poison the sentinel comm buffers ourselves (also needed for the un-timed correctness call)
    hipMemsetAsync(comm1, 0xAA, (size_t)T_SEQ * (H1/2) * 4, stream);
    hipMemsetAsync(comm2, 0xAA, (size_t)T_SEQ * H2 * 4, stream);

    // f32 -> bf16 conversions
    cvt_bf16_kernel<<<2048, 256, 0, stream>>>(x_f,    xb,    T_SEQ * IN_SZ);
    cvt_bf16_kernel<<<2048, 256, 0, stream>>>(wih1_f, wih1b, G1 * IN_SZ);
    cvt_bf16_kernel<<<2048, 256, 0, stream>>>(whh1_f, whh1b, G1 * H1);
    cvt_bf16_kernel<<<2048, 256, 0, stream>>>(wih2_f, wih2b, G2 * H1);
    cvt_bf16_kernel<<<4096, 256, 0, stream>>>(whh2_f, whh2b, G2 * H2);

    // pre1 = x @ wih1^T + (bih1 + bhh1)   [bf16 out]
    {
        dim3 grid(G1 / 64, T_SEQ / 64);
        gemm_bt_kernel<true><<<grid, 256, 0, stream>>>(xb, wih1b, (float*)nullptr, pre1,
                                                       bih1, bhh1, T_SEQ, G1, IN_SZ);
    }
    // layer-1 recurrence: 64 blocks, 16 units/block, LDS = 128KB weights + 8KB h
    {
        size_t shmem = (size_t)4 * 16 * H1 * 2 + (size_t)2 * H1 * 4;
        lstm_rec_kernel<H1, 16, 16, true><<<64, 256, shmem, stream>>>(
            pre1, whh1b, comm1, T_SEQ);
    }
    // pre2 = h1 @ wih2^T + (bih2 + bhh2)  [bf16 out]; comm1 IS row-major bf16 [T,H1]
    {
        dim3 grid(G2 / 64, T_SEQ / 64);
        gemm_bt_kernel<true><<<grid, 256, 0, stream>>>((const ushort_t*)comm1, wih2b,
                                                       (float*)nullptr, pre2,
                                                       bih2, bhh2, T_SEQ, G2, H1);
    }
    // layer-2 recurrence: 256 blocks, 8 units/block, LDS = 128KB weights + 16KB h
    {
        size_t shmem = (size_t)4 * 8 * H2 * 2 + (size_t)2 * H2 * 4;
        lstm_rec_kernel<H2, 8, 32, false><<<256, 256, shmem, stream>>>(
            pre2, whh2b, comm2, T_SEQ);
    }

    // p1 = wl1 . h2[T-1] + bl1 ; out = wl2 . p1 + bl2
    const float* h2_last = (const float*)(comm2 + (size_t)(T_SEQ - 1) * H2);
    linear_vec_kernel<<<L1OUT / 4, 256, 0, stream>>>(wl1, bl1, h2_last, p1, L1OUT, H2);
    linear_vec_kernel<<<OUT_SZ / 4, 256, 0, stream>>>(wl2, bl2, p1, (float*)d_out, OUT_SZ, L1OUT);

    (void)in_sizes; (void)n_in; (void)out_size; (void)ws_size;
}

// Round 5
// 21938.208 us; speedup vs baseline: 3.1817x; 1.5870x over previous
//
#include <hip/hip_runtime.h>
#include <stdint.h>

typedef unsigned short ushort_t;
typedef __attribute__((ext_vector_type(8))) short short8;
typedef __attribute__((ext_vector_type(4))) float f32x4;

#define T_SEQ 4096
#define IN_SZ 512
#define H1 1024
#define H2 2048
#define G1 (4*H1)   // 4096
#define G2 (4*H2)   // 8192
#define OUT_SZ 512
#define L1OUT 1024

#define SENT 0xAAAAAAAAu

__device__ __forceinline__ ushort_t f32_to_bf16(float f) {
    union { float f; uint32_t u; } x; x.f = f;
    uint32_t u = x.u;
    uint32_t r = (u + 0x7fffu + ((u >> 16) & 1u)) >> 16;
    return (ushort_t)r;
}
__device__ __forceinline__ float bf16_lo(uint32_t p) {
    union { uint32_t u; float f; } x; x.u = p << 16; return x.f;
}
__device__ __forceinline__ float bf16_hi(uint32_t p) {
    union { uint32_t u; float f; } x; x.u = p & 0xffff0000u; return x.f;
}
__device__ __forceinline__ float bf16_val(ushort_t v) {
    union { uint32_t u; float f; } x; x.u = ((uint32_t)v) << 16; return x.f;
}
// fast gate math: v_exp_f32 + v_rcp_f32 based (error ~2ulp, far under the 1e-3 budget)
__device__ __forceinline__ float fsig(float x) {
    return __builtin_amdgcn_rcpf(1.0f + __expf(-x));
}
__device__ __forceinline__ float ftanh(float x) {
    return 1.0f - 2.0f * __builtin_amdgcn_rcpf(__expf(2.0f * x) + 1.0f);
}

#define DOT8(ACC, WV, A4, B4) do { \
    ACC = fmaf(bf16_lo((WV).x), (A4)[0], ACC); ACC = fmaf(bf16_hi((WV).x), (A4)[1], ACC); \
    ACC = fmaf(bf16_lo((WV).y), (A4)[2], ACC); ACC = fmaf(bf16_hi((WV).y), (A4)[3], ACC); \
    ACC = fmaf(bf16_lo((WV).z), (B4)[0], ACC); ACC = fmaf(bf16_hi((WV).z), (B4)[1], ACC); \
    ACC = fmaf(bf16_lo((WV).w), (B4)[2], ACC); ACC = fmaf(bf16_hi((WV).w), (B4)[3], ACC); } while (0)

// ---------------- f32 -> bf16 conversion ----------------
__global__ __launch_bounds__(256) void cvt_bf16_kernel(const float* __restrict__ in,
                                                       ushort_t* __restrict__ out, int n) {
    int i = blockIdx.x * 256 + threadIdx.x;
    int stride = gridDim.x * 256;
    for (; i < n; i += stride) out[i] = f32_to_bf16(in[i]);
}

// ---------------- bf16 MFMA GEMM: C[M,N] = A[M,K] * B[N,K]^T + bias_a[n] + bias_b[n] ----------------
__global__ __launch_bounds__(256) void gemm_bt_kernel(const ushort_t* __restrict__ A,
                                                      const ushort_t* __restrict__ B,
                                                      ushort_t* __restrict__ Cb,
                                                      const float* __restrict__ bias_a,
                                                      const float* __restrict__ bias_b,
                                                      int M, int N, int K) {
    int tid  = threadIdx.x;
    int wave = tid >> 6;
    int lane = tid & 63;
    int l15  = lane & 15;
    int quad = lane >> 4;
    int m0 = blockIdx.y * 64 + wave * 16;
    int n0 = blockIdx.x * 64;

    const ushort_t* pa = A + (size_t)(m0 + l15) * K + quad * 8;
    f32x4 acc[4];
    #pragma unroll
    for (int i = 0; i < 4; ++i) acc[i] = (f32x4){0.f, 0.f, 0.f, 0.f};

    for (int kc = 0; kc < K; kc += 32) {
        short8 a = *(const short8*)(pa + kc);
        #pragma unroll
        for (int nf = 0; nf < 4; ++nf) {
            const ushort_t* pb = B + (size_t)(n0 + nf * 16 + l15) * K + quad * 8 + kc;
            short8 b = *(const short8*)pb;
            acc[nf] = __builtin_amdgcn_mfma_f32_16x16x32_bf16(a, b, acc[nf], 0, 0, 0);
        }
    }

    int rbase = quad * 4;
    #pragma unroll
    for (int nf = 0; nf < 4; ++nf) {
        int n = n0 + nf * 16 + l15;
        float bb = bias_a[n] + bias_b[n];
        #pragma unroll
        for (int r = 0; r < 4; ++r) {
            int m = m0 + rbase + r;
            Cb[(size_t)m * N + n] = f32_to_bf16(acc[nf][r] + bb);
        }
    }
}

// ---------------- Fused 2-layer LSTM recurrence: ONE global sync round per step ----------------
// 256 blocks x 256 threads (1 block/CU, persistent). Block b owns h1 units [4b,4b+4) and
// h2 units [8b,8b+8). Mega-step s: compute h1[s] (whh1 @ h1[s-1] + pre1[s]), pre2[s-1]
// (wih2-slice @ h1[s-1], block-LOCAL: the needed 32 wih2 rows are exactly this block's h2
// gate rows), h2[s-1] (whh2 @ h2[s-2] + pre2[s-1]). Publish h1[s], h2[s-1]; poll both next
// step (sentinel data-as-signal). LDS: whh1 32KB + wih2 64KB + whh2-g0 32KB + h bufs 24KB
// = 152KB. whh2 gates 1..3 (96KB/step) stream from per-XCD L2 (3MB/XCD footprint) via
// register prefetch issued before the poll. h arrays de-interleaved (even/odd 4-float) for
// conflict-free b128 LDS reads; parity double-buffered -> one barrier per step.
__global__ __launch_bounds__(256, 1) void fused_lstm_kernel(
        const ushort_t* __restrict__ pre1,    // bf16 [T, 4096]
        const ushort_t* __restrict__ whh1b,   // bf16 [4096, 1024]
        const ushort_t* __restrict__ wih2b,   // bf16 [8192, 1024]
        const ushort_t* __restrict__ whh2b,   // bf16 [8192, 2048]
        const float* __restrict__ bih2,
        const float* __restrict__ bhh2,
        uint32_t* __restrict__ comm1,         // f32 bits [T, 1024], pre-poisoned 0xAA
        uint32_t* __restrict__ comm2,         // f32 bits [T, 2048], pre-poisoned 0xAA
        int T) {
    extern __shared__ char smem[];
    uint32_t* whh1_w = (uint32_t*)smem;            // [16][512]  u32 pairs (32KB)
    uint32_t* wih2_w = whh1_w + 16 * 512;          // [32][512]  (64KB)
    uint32_t* whh2_w = wih2_w + 32 * 512;          // [8][1024]  gate0 resident (32KB)
    float*    h1b    = (float*)(whh2_w + 8 * 1024);// [2][2][512]  (8KB)  parity/arr
    float*    h2b    = h1b + 2 * 1024;             // [2][2][1024] (16KB)

    int tid = threadIdx.x;
    int blk = blockIdx.x;
    int u1  = tid >> 6;          // h1 unit (0..3), 64 lanes each
    int ln1 = tid & 63;
    int u2l = tid >> 5;          // h2 unit (0..7), 32 lanes each
    int ln2 = tid & 31;
    int wv  = tid >> 6;          // wave id (0..3)

    // ---- stage resident weights into LDS ----
    #pragma unroll
    for (int i = 0; i < 8; ++i) {            // whh1: 16 rows x 128 uint4
        int idx = tid + i * 256, r = idx >> 7, ch = idx & 127;
        size_t R = (size_t)(r & 3) * H1 + blk * 4 + (r >> 2);
        *(uint4*)&whh1_w[r * 512 + ch * 4] = *(const uint4*)(whh1b + R * H1 + ch * 8);
    }
    #pragma unroll
    for (int i = 0; i < 16; ++i) {           // wih2: 32 rows x 128 uint4
        int idx = tid + i * 256, r = idx >> 7, ch = idx & 127;
        size_t R = (size_t)(r & 3) * H2 + blk * 8 + (r >> 2);
        *(uint4*)&wih2_w[r * 512 + ch * 4] = *(const uint4*)(wih2b + R * H1 + ch * 8);
    }
    #pragma unroll
    for (int i = 0; i < 8; ++i) {            // whh2 gate0: 8 rows x 256 uint4
        int idx = tid + i * 256, r = idx >> 8, ch = idx & 255;
        size_t R = (size_t)(blk * 8 + r);
        *(uint4*)&whh2_w[r * 1024 + ch * 4] = *(const uint4*)(whh2b + R * H2 + ch * 8);
    }

    // per-unit layer-2 bias (used by lane ln2==0)
    float b2g[4];
    {
        int U = blk * 8 + u2l;
        #pragma unroll
        for (int g = 0; g < 4; ++g) b2g[g] = bih2[g * H2 + U] + bhh2[g * H2 + U];
    }

    // pre1 prefetch pipeline (lane ln1==0 of each h1 unit)
    float pc[4] = {0.f, 0.f, 0.f, 0.f};
    if (ln1 == 0) {
        #pragma unroll
        for (int g = 0; g < 4; ++g)
            pc[g] = bf16_val(pre1[(size_t)0 * G1 + g * H1 + blk * 4 + u1]);
    }

    float c1 = 0.0f;   // valid on ln1==0
    float c2 = 0.0f;   // valid on ln2==0

    for (int s = 0; s <= T; ++s) {
        // ---- prefetch pre1[s+1] (HBM latency hidden behind poll) ----
        float pn[4] = {0.f, 0.f, 0.f, 0.f};
        if (ln1 == 0) {
            int row = (s + 1 < T) ? s + 1 : T - 1;
            #pragma unroll
            for (int g = 0; g < 4; ++g)
                pn[g] = bf16_val(pre1[(size_t)row * G1 + g * H1 + blk * 4 + u1]);
        }
        // ---- prefetch streamed whh2 gates 1..3 from L2 (loop-invariant addresses) ----
        uint4 wreg[24];
        if (s >= 2) {
            #pragma unroll
            for (int g = 1; g < 4; ++g) {
                size_t R = (size_t)g * H2 + blk * 8 + u2l;
                #pragma unroll
                for (int j = 0; j < 8; ++j)
                    wreg[(g - 1) * 8 + j] =
                        *(const uint4*)(whh2b + R * H2 + ln2 * 8 + j * 256);
            }
        }

        // ---- batched sentinel poll of h1[s-1] and h2[s-2]; stage de-interleaved ----
        if (s >= 1) {
            const uint32_t* s1 = comm1 + (size_t)(s - 1) * H1;
            const uint32_t* s2 = comm2 + (size_t)(s - 2) * H2;  // valid only if s>=2
            uint32_t v1[4], v2[8];
            bool need2 = (s >= 2);
            for (;;) {
                #pragma unroll
                for (int k = 0; k < 4; ++k)
                    v1[k] = __hip_atomic_load(&s1[tid + k * 256], __ATOMIC_RELAXED,
                                              __HIP_MEMORY_SCOPE_AGENT);
                if (need2) {
                    #pragma unroll
                    for (int k = 0; k < 8; ++k)
                        v2[k] = __hip_atomic_load(&s2[tid + k * 256], __ATOMIC_RELAXED,
                                                  __HIP_MEMORY_SCOPE_AGENT);
                }
                bool bad = false;
                #pragma unroll
                for (int k = 0; k < 4; ++k) bad |= (v1[k] == SENT);
                if (need2) {
                    #pragma unroll
                    for (int k = 0; k < 8; ++k) bad |= (v2[k] == SENT);
                }
                if (!bad) break;
                __builtin_amdgcn_s_sleep(1);
            }
            float* d1 = h1b + ((s - 1) & 1) * 1024;
            #pragma unroll
            for (int k = 0; k < 4; ++k) {
                int w = tid + k * 256;
                union { uint32_t u; float f; } x; x.u = v1[k];
                d1[((w >> 2) & 1) * 512 + ((w >> 3) << 2) + (w & 3)] = x.f;
            }
            if (need2) {
                float* d2 = h2b + (s & 1) * 2048;
                #pragma unroll
                for (int k = 0; k < 8; ++k) {
                    int w = tid + k * 256;
                    union { uint32_t u; float f; } x; x.u = v2[k];
                    d2[((w >> 2) & 1) * 1024 + ((w >> 3) << 2) + (w & 3)] = x.f;
                }
            }
        }
        __syncthreads();   // the only barrier per step

        const float* h1p = h1b + ((s - 1) & 1) * 1024;  // h1[s-1] (valid s>=1)

        // ============ layer-1: h1[s] ============
        if (s < T) {
            float a0 = 0.f, a1 = 0.f, a2 = 0.f, a3 = 0.f;
            if (s >= 1) {
                #pragma unroll
                for (int j = 0; j < 2; ++j) {
                    int kp = ln1 * 4 + j * 256;
                    f32x4 ha = *(const f32x4*)&h1p[(ln1 + j * 64) * 4];
                    f32x4 hb = *(const f32x4*)&h1p[512 + (ln1 + j * 64) * 4];
                    uint4 w0 = *(const uint4*)&whh1_w[(u1 * 4 + 0) * 512 + kp];
                    uint4 w1 = *(const uint4*)&whh1_w[(u1 * 4 + 1) * 512 + kp];
                    uint4 w2 = *(const uint4*)&whh1_w[(u1 * 4 + 2) * 512 + kp];
                    uint4 w3 = *(const uint4*)&whh1_w[(u1 * 4 + 3) * 512 + kp];
                    DOT8(a0, w0, ha, hb); DOT8(a1, w1, ha, hb);
                    DOT8(a2, w2, ha, hb); DOT8(a3, w3, ha, hb);
                }
            }
            #pragma unroll
            for (int off = 32; off > 0; off >>= 1) {
                a0 += __shfl_down(a0, off, 64); a1 += __shfl_down(a1, off, 64);
                a2 += __shfl_down(a2, off, 64); a3 += __shfl_down(a3, off, 64);
            }
            if (ln1 == 0) {
                float iv = fsig(pc[0] + a0);
                float fv = fsig(pc[1] + a1);
                float gv = ftanh(pc[2] + a2);
                float ov = fsig(pc[3] + a3);
                c1 = fv * c1 + iv * gv;
                float h = ov * ftanh(c1);
                union { float f; uint32_t u; } x; x.f = h;
                __hip_atomic_store(&comm1[(size_t)s * H1 + blk * 4 + u1], x.u,
                                   __ATOMIC_RELAXED, __HIP_MEMORY_SCOPE_AGENT);
            }
        }

        // ============ layer-2: pre2[s-1] (local) + h2[s-1] ============
        if (s >= 1) {
            // --- pre2: wave wv computes rows wv*8..wv*8+7 of this block's wih2 slice ---
            float pv[8];
            #pragma unroll
            for (int d = 0; d < 8; ++d) pv[d] = 0.f;
            {
                f32x4 ha0 = *(const f32x4*)&h1p[ln1 * 4];
                f32x4 hb0 = *(const f32x4*)&h1p[512 + ln1 * 4];
                f32x4 ha1 = *(const f32x4*)&h1p[(ln1 + 64) * 4];
                f32x4 hb1 = *(const f32x4*)&h1p[512 + (ln1 + 64) * 4];
                #pragma unroll
                for (int d = 0; d < 8; ++d) {
                    int r = wv * 8 + d;
                    uint4 w0 = *(const uint4*)&wih2_w[r * 512 + ln1 * 4];
                    uint4 w1 = *(const uint4*)&wih2_w[r * 512 + ln1 * 4 + 256];
                    DOT8(pv[d], w0, ha0, hb0);
                    DOT8(pv[d], w1, ha1, hb1);
                }
            }
            #pragma unroll
            for (int off = 32; off > 0; off >>= 1) {
                #pragma unroll
                for (int d = 0; d < 8; ++d) pv[d] += __shfl_down(pv[d], off, 64);
            }
            float pb[8];
            #pragma unroll
            for (int d = 0; d < 8; ++d) pb[d] = __shfl(pv[d], 0, 64);  // broadcast from wave lane0

            // --- whh2 matvec (h2[s-2]); gate0 from LDS, gates 1..3 from streamed regs ---
            float b0 = 0.f, b1 = 0.f, b2 = 0.f, b3 = 0.f;
            if (s >= 2) {
                const float* h2p = h2b + (s & 1) * 2048;
                #pragma unroll
                for (int j = 0; j < 8; ++j) {
                    f32x4 xa = *(const f32x4*)&h2p[(ln2 + j * 32) * 4];
                    f32x4 xb = *(const f32x4*)&h2p[1024 + (ln2 + j * 32) * 4];
                    uint4 w0 = *(const uint4*)&whh2_w[u2l * 1024 + ln2 * 4 + j * 128];
                    DOT8(b0, w0, xa, xb);
                    DOT8(b1, wreg[0 * 8 + j], xa, xb);
                    DOT8(b2, wreg[1 * 8 + j], xa, xb);
                    DOT8(b3, wreg[2 * 8 + j], xa, xb);
                }
            }
            #pragma unroll
            for (int off = 16; off > 0; off >>= 1) {
                b0 += __shfl_down(b0, off, 32); b1 += __shfl_down(b1, off, 32);
                b2 += __shfl_down(b2, off, 32); b3 += __shfl_down(b3, off, 32);
            }
            if (ln2 == 0) {
                int half = u2l & 1;   // which of the wave's 2 units
                float iv = fsig(pb[half * 4 + 0] + b2g[0] + b0);
                float fv = fsig(pb[half * 4 + 1] + b2g[1] + b1);
                float gv = ftanh(pb[half * 4 + 2] + b2g[2] + b2);
                float ov = fsig(pb[half * 4 + 3] + b2g[3] + b3);
                c2 = fv * c2 + iv * gv;
                float h = ov * ftanh(c2);
                union { float f; uint32_t u; } x; x.f = h;
                __hip_atomic_store(&comm2[(size_t)(s - 1) * H2 + blk * 8 + u2l], x.u,
                                   __ATOMIC_RELAXED, __HIP_MEMORY_SCOPE_AGENT);
            }
        }

        #pragma unroll
        for (int g = 0; g < 4; ++g) pc[g] = pn[g];
    }
}

// ---------------- small matvec: out[j] = W[j,:K] . x + bias[j], one wave per output ----------------
__global__ __launch_bounds__(256) void linear_vec_kernel(const float* __restrict__ W,
                                                         const float* __restrict__ bias,
                                                         const float* __restrict__ x,
                                                         float* __restrict__ out,
                                                         int N, int K) {
    int wave = threadIdx.x >> 6;
    int lane = threadIdx.x & 63;
    int j = blockIdx.x * 4 + wave;
    if (j >= N) return;
    const float* wr = W + (size_t)j * K;
    float s = 0.0f;
    for (int k = lane; k < K; k += 64) s += wr[k] * x[k];
    #pragma unroll
    for (int off = 32; off > 0; off >>= 1) s += __shfl_down(s, off, 64);
    if (lane == 0) out[j] = s + bias[j];
}

extern "C" void kernel_launch(void* const* d_in, const int* in_sizes, int n_in,
                              void* d_out, int out_size, void* d_ws, size_t ws_size,
                              hipStream_t stream) {
    const float* x_f    = (const float*)d_in[0];
    const float* wih1_f = (const float*)d_in[1];
    const float* whh1_f = (const float*)d_in[2];
    const float* bih1   = (const float*)d_in[3];
    const float* bhh1   = (const float*)d_in[4];
    const float* wih2_f = (const float*)d_in[5];
    const float* whh2_f = (const float*)d_in[6];
    const float* bih2   = (const float*)d_in[7];
    const float* bhh2   = (const float*)d_in[8];
    const float* wl1    = (const float*)d_in[9];
    const float* bl1    = (const float*)d_in[10];
    const float* wl2    = (const float*)d_in[11];
    const float* bl2    = (const float*)d_in[12];

    uint8_t* base = (uint8_t*)d_ws;
    size_t off = 0;
    auto alloc = [&](size_t bytes) { size_t o = off; off = (off + bytes + 255) & ~(size_t)255; return o; };

    size_t pre1_off  = alloc((size_t)T_SEQ * G1 * 2);   // bf16 [T,4096]
    size_t comm1_off = alloc((size_t)T_SEQ * H1 * 4);   // f32 [T,1024]
    size_t comm2_off = alloc((size_t)T_SEQ * H2 * 4);   // f32 [T,2048]
    size_t whh1_off  = alloc((size_t)G1 * H1 * 2);
    size_t whh2_off  = alloc((size_t)G2 * H2 * 2);
    size_t wih1_off  = alloc((size_t)G1 * IN_SZ * 2);
    size_t wih2_off  = alloc((size_t)G2 * H1 * 2);
    size_t xb_off    = alloc((size_t)T_SEQ * IN_SZ * 2);
    size_t p1_off    = alloc((size_t)L1OUT * 4);

    ushort_t* pre1  = (ushort_t*)(base + pre1_off);
    uint32_t* comm1 = (uint32_t*)(base + comm1_off);
    uint32_t* comm2 = (uint32_t*)(base + comm2_off);
    ushort_t* whh1b = (ushort_t*)(base + whh1_off);
    ushort_t* whh2b = (ushort_t*)(base + whh2_off);
    ushort_t* wih1b = (ushort_t*)(base + wih1_off);
    ushort_t* wih2b = (ushort_t*)(base + wih2_off);
    ushort_t* xb    = (ushort_t*)(base + xb_off);
    float*    p1    = (float*)(base + p1_off);

    // poison the sentinel comm buffers (data-as-signal)
    hipMemsetAsync(comm1, 0xAA, (size_t)T_SEQ * H1 * 4, stream);
    hipMemsetAsync(comm2, 0xAA, (size_t)T_SEQ * H2 * 4, stream);

    // f32 -> bf16 conversions
    cvt_bf16_kernel<<<2048, 256, 0, stream>>>(x_f,    xb,    T_SEQ * IN_SZ);
    cvt_bf16_kernel<<<2048, 256, 0, stream>>>(wih1_f, wih1b, G1 * IN_SZ);
    cvt_bf16_kernel<<<2048, 256, 0, stream>>>(whh1_f, whh1b, G1 * H1);
    cvt_bf16_kernel<<<2048, 256, 0, stream>>>(wih2_f, wih2b, G2 * H1);
    cvt_bf16_kernel<<<4096, 256, 0, stream>>>(whh2_f, whh2b, G2 * H2);

    // pre1 = x @ wih1^T + (bih1 + bhh1)   [bf16 out]
    {
        dim3 grid(G1 / 64, T_SEQ / 64);
        gemm_bt_kernel<<<grid, 256, 0, stream>>>(xb, wih1b, pre1, bih1, bhh1,
                                                 T_SEQ, G1, IN_SZ);
    }

    // fused 2-layer recurrence: 256 blocks, 152KB dynamic LDS
    {
        size_t shmem = (size_t)(16 * 512 + 32 * 512 + 8 * 1024) * 4   // weights
                     + (size_t)(2 * 1024 + 2 * 2048) * 4;             // h parity bufs
        fused_lstm_kernel<<<256, 256, shmem, stream>>>(
            pre1, whh1b, wih2b, whh2b, bih2, bhh2, comm1, comm2, T_SEQ);
    }

    // p1 = wl1 . h2[T-1] + bl1 ; out = wl2 . p1 + bl2
    const float* h2_last = (const float*)(comm2 + (size_t)(T_SEQ - 1) * H2);
    linear_vec_kernel<<<L1OUT / 4, 256, 0, stream>>>(wl1, bl1, h2_last, p1, L1OUT, H2);
    linear_vec_kernel<<<OUT_SZ / 4, 256, 0, stream>>>(wl2, bl2, p1, (float*)d_out, OUT_SZ, L1OUT);

    (void)in_sizes; (void)n_in; (void)out_size; (void)ws_size;
}

// Round 7
// 17064.519 us; speedup vs baseline: 4.0905x; 1.2856x over previous
//
#include <hip/hip_runtime.h>
#include <stdint.h>

typedef unsigned short ushort_t;
typedef _Float16 f16_t;
typedef __attribute__((ext_vector_type(2))) _Float16 half2;
typedef __attribute__((ext_vector_type(8))) _Float16 half8;
typedef __attribute__((ext_vector_type(4))) float f32x4;

#define T_SEQ 4096
#define IN_SZ 512
#define H1 1024
#define H2 2048
#define G1 (4*H1)   // 4096
#define G2 (4*H2)   // 8192
#define OUT_SZ 512
#define L1OUT 1024

#define SENT 0xAAAAAAAAu

__device__ __forceinline__ float f16_val(ushort_t v) {
    union { ushort_t u; _Float16 h; } x; x.u = v; return (float)x.h;
}
__device__ __forceinline__ half2 u2h(uint32_t w) {
    union { uint32_t u; half2 h; } x; x.u = w; return x.h;
}
__device__ __forceinline__ uint32_t pack_f16(float a, float b) {
    auto h = __builtin_amdgcn_cvt_pkrtz(a, b);   // __fp16 ext_vector(2) on gfx950
    union { decltype(h) h; uint32_t u; } x; x.h = h; return x.u;
}
// fast gate math
__device__ __forceinline__ float fsig(float x) {
    return __builtin_amdgcn_rcpf(1.0f + __expf(-x));
}
__device__ __forceinline__ float ftanh(float x) {
    return 1.0f - 2.0f * __builtin_amdgcn_rcpf(__expf(2.0f * x) + 1.0f);
}

// 2 MACs: acc += w·h for one packed f16 pair
__device__ __forceinline__ void dot2(float& acc, uint32_t w, uint32_t h) {
#if defined(__has_builtin) && __has_builtin(__builtin_amdgcn_fdot2)
    acc = __builtin_amdgcn_fdot2(u2h(w), u2h(h), acc, false);
#else
    half2 a = u2h(w), b = u2h(h);
    acc = fmaf((float)a.x, (float)b.x, acc);
    acc = fmaf((float)a.y, (float)b.y, acc);
#endif
}
#define DOT4(ACC, W, Hv) do { dot2(ACC, (W).x, (Hv).x); dot2(ACC, (W).y, (Hv).y); \
                              dot2(ACC, (W).z, (Hv).z); dot2(ACC, (W).w, (Hv).w); } while (0)

// ---------------- f32 -> f16 conversion ----------------
__global__ __launch_bounds__(256) void cvt_f16_kernel(const float* __restrict__ in,
                                                      f16_t* __restrict__ out, int n) {
    int i = blockIdx.x * 256 + threadIdx.x;
    int stride = gridDim.x * 256;
    for (; i < n; i += stride) out[i] = (f16_t)in[i];
}

// ---------------- f16 MFMA GEMM: C[M,N] = A[M,K] * B[N,K]^T + bias_a + bias_b, f16 out ----------
__global__ __launch_bounds__(256) void gemm_bt_kernel(const f16_t* __restrict__ A,
                                                      const f16_t* __restrict__ B,
                                                      f16_t* __restrict__ Cb,
                                                      const float* __restrict__ bias_a,
                                                      const float* __restrict__ bias_b,
                                                      int M, int N, int K) {
    int tid  = threadIdx.x;
    int wave = tid >> 6;
    int lane = tid & 63;
    int l15  = lane & 15;
    int quad = lane >> 4;
    int m0 = blockIdx.y * 64 + wave * 16;
    int n0 = blockIdx.x * 64;

    const f16_t* pa = A + (size_t)(m0 + l15) * K + quad * 8;
    f32x4 acc[4];
    #pragma unroll
    for (int i = 0; i < 4; ++i) acc[i] = (f32x4){0.f, 0.f, 0.f, 0.f};

    for (int kc = 0; kc < K; kc += 32) {
        half8 a = *(const half8*)(pa + kc);
        #pragma unroll
        for (int nf = 0; nf < 4; ++nf) {
            const f16_t* pb = B + (size_t)(n0 + nf * 16 + l15) * K + quad * 8 + kc;
            half8 b = *(const half8*)pb;
            acc[nf] = __builtin_amdgcn_mfma_f32_16x16x32_f16(a, b, acc[nf], 0, 0, 0);
        }
    }

    int rbase = quad * 4;
    #pragma unroll
    for (int nf = 0; nf < 4; ++nf) {
        int n = n0 + nf * 16 + l15;
        float bb = bias_a[n] + bias_b[n];
        #pragma unroll
        for (int r = 0; r < 4; ++r) {
            int m = m0 + rbase + r;
            Cb[(size_t)m * N + n] = (f16_t)(acc[nf][r] + bb);
        }
    }
}

// ---------------- Fused 2-layer LSTM recurrence, split-phase pipeline ----------------
// 256 blocks x 256 threads (1 block/CU, persistent). Block b owns h1 units [4b,4b+4),
// h2 units [8b,8b+8). Iteration s:
//   A: poll h1[s-1] (published mid prev iter -> slack), stage packed-f16, barrier A
//   B: h1[s] = gates(whh1·h1[s-1] + pre1[s]), publish f32; pre2[s-1] = wih2-slice·h1[s-1]
//   B': poll h2[s-2] (published END of prev iter; slack = A+B phases), stage, barrier B
//   C: h2[s-1] = gates(whh2·h2[s-2] + pre2[s-1]), publish f32
// Dots use v_dot2_f32_f16 on packed-f16 LDS data (2 MACs/inst, no unpack). whh2 gates 1..3
// stream from per-XCD L2 into regs (prefetched at iter start). comm buffers are f32,
// sentinel data-as-signal (0xAA), 64-bit poll loads.
__global__ __launch_bounds__(256, 1) void fused_lstm_kernel(
        const f16_t* __restrict__ pre1,       // f16 [T, 4096]
        const ushort_t* __restrict__ whh1h,   // f16 bits [4096, 1024]
        const ushort_t* __restrict__ wih2h,   // f16 bits [8192, 1024]
        const ushort_t* __restrict__ whh2h,   // f16 bits [8192, 2048]
        const float* __restrict__ bih2,
        const float* __restrict__ bhh2,
        uint32_t* __restrict__ comm1,         // f32 bits [T, 1024], pre-poisoned 0xAA
        uint32_t* __restrict__ comm2,         // f32 bits [T, 2048], pre-poisoned 0xAA
        int T) {
    extern __shared__ char smem[];
    uint32_t* whh1_w = (uint32_t*)smem;             // [16][512]  f16-pair words (32KB)
    uint32_t* wih2_w = whh1_w + 16 * 512;           // [32][512]  (64KB)
    uint32_t* whh2_w = wih2_w + 32 * 512;           // [8][1024]  gate0 (32KB)
    uint32_t* h1b    = whh2_w + 8 * 1024;           // [2][512]   packed h1 (4KB)
    uint32_t* h2b    = h1b + 2 * 512;               // [2][1024]  packed h2 (8KB)

    int tid = threadIdx.x;
    int blk = blockIdx.x;
    int u1  = tid >> 6;          // h1 unit (0..3), 64 lanes
    int ln1 = tid & 63;
    int u2l = tid >> 5;          // h2 unit (0..7), 32 lanes
    int ln2 = tid & 31;
    int wv  = tid >> 6;          // wave id

    // ---- stage resident weights into LDS (f16 bytes, same layout as the global rows) ----
    #pragma unroll
    for (int i = 0; i < 8; ++i) {            // whh1: 16 rows x 128 uint4
        int idx = tid + i * 256, r = idx >> 7, ch = idx & 127;
        size_t R = (size_t)(r & 3) * H1 + blk * 4 + (r >> 2);
        *(uint4*)&whh1_w[r * 512 + ch * 4] = *(const uint4*)(whh1h + R * H1 + ch * 8);
    }
    #pragma unroll
    for (int i = 0; i < 16; ++i) {           // wih2: 32 rows x 128 uint4
        int idx = tid + i * 256, r = idx >> 7, ch = idx & 127;
        size_t R = (size_t)(r & 3) * H2 + blk * 8 + (r >> 2);
        *(uint4*)&wih2_w[r * 512 + ch * 4] = *(const uint4*)(wih2h + R * H1 + ch * 8);
    }
    #pragma unroll
    for (int i = 0; i < 8; ++i) {            // whh2 gate0: 8 rows x 256 uint4
        int idx = tid + i * 256, r = idx >> 8, ch = idx & 255;
        size_t R = (size_t)(blk * 8 + r);
        *(uint4*)&whh2_w[r * 1024 + ch * 4] = *(const uint4*)(whh2h + R * H2 + ch * 8);
    }

    float b2g[4];
    {
        int U = blk * 8 + u2l;
        #pragma unroll
        for (int g = 0; g < 4; ++g) b2g[g] = bih2[g * H2 + U] + bhh2[g * H2 + U];
    }

    float pc[4] = {0.f, 0.f, 0.f, 0.f};
    if (ln1 == 0) {
        #pragma unroll
        for (int g = 0; g < 4; ++g)
            pc[g] = f16_val(((const ushort_t*)pre1)[(size_t)0 * G1 + g * H1 + blk * 4 + u1]);
    }

    float c1 = 0.0f;   // ln1==0
    float c2 = 0.0f;   // ln2==0

    for (int s = 0; s <= T; ++s) {
        // ---- prefetch pre1[s+1] and streamed whh2 gates 1..3 (L2) ----
        float pn[4] = {0.f, 0.f, 0.f, 0.f};
        if (ln1 == 0) {
            int row = (s + 1 < T) ? s + 1 : T - 1;
            #pragma unroll
            for (int g = 0; g < 4; ++g)
                pn[g] = f16_val(((const ushort_t*)pre1)[(size_t)row * G1 + g * H1 + blk * 4 + u1]);
        }
        uint4 wreg[24];
        if (s >= 2) {
            #pragma unroll
            for (int g = 1; g < 4; ++g) {
                size_t R = (size_t)g * H2 + blk * 8 + u2l;
                #pragma unroll
                for (int j = 0; j < 8; ++j)
                    wreg[(g - 1) * 8 + j] =
                        *(const uint4*)(whh2h + R * H2 + ln2 * 8 + j * 256);
            }
        }

        // ---- Phase A: poll h1[s-1] (64-bit loads), stage packed f16 ----
        if (s >= 1) {
            const uint64_t* s1 = (const uint64_t*)(comm1 + (size_t)(s - 1) * H1);
            uint64_t q0, q1;
            for (;;) {
                q0 = __hip_atomic_load(&s1[tid],       __ATOMIC_RELAXED, __HIP_MEMORY_SCOPE_AGENT);
                q1 = __hip_atomic_load(&s1[tid + 256], __ATOMIC_RELAXED, __HIP_MEMORY_SCOPE_AGENT);
                if ((uint32_t)q0 != SENT && (uint32_t)(q0 >> 32) != SENT &&
                    (uint32_t)q1 != SENT && (uint32_t)(q1 >> 32) != SENT) break;
                __builtin_amdgcn_s_sleep(1);
            }
            uint32_t* d = h1b + ((s - 1) & 1) * 512;
            union { uint64_t q; float f[2]; } x;
            x.q = q0; d[tid]       = pack_f16(x.f[0], x.f[1]);
            x.q = q1; d[tid + 256] = pack_f16(x.f[0], x.f[1]);
        }
        __syncthreads();   // barrier A

        const uint32_t* h1p = h1b + ((s - 1) & 1) * 512;
        uint4 hA, hB;
        if (s >= 1) {
            hA = *(const uint4*)&h1p[ln1 * 4];
            hB = *(const uint4*)&h1p[ln1 * 4 + 256];
        }

        // ---- Phase B: h1[s] ----
        if (s < T) {
            float a0 = 0.f, a1 = 0.f, a2 = 0.f, a3 = 0.f;
            if (s >= 1) {
                uint4 w;
                w = *(const uint4*)&whh1_w[(u1 * 4 + 0) * 512 + ln1 * 4];       DOT4(a0, w, hA);
                w = *(const uint4*)&whh1_w[(u1 * 4 + 0) * 512 + ln1 * 4 + 256]; DOT4(a0, w, hB);
                w = *(const uint4*)&whh1_w[(u1 * 4 + 1) * 512 + ln1 * 4];       DOT4(a1, w, hA);
                w = *(const uint4*)&whh1_w[(u1 * 4 + 1) * 512 + ln1 * 4 + 256]; DOT4(a1, w, hB);
                w = *(const uint4*)&whh1_w[(u1 * 4 + 2) * 512 + ln1 * 4];       DOT4(a2, w, hA);
                w = *(const uint4*)&whh1_w[(u1 * 4 + 2) * 512 + ln1 * 4 + 256]; DOT4(a2, w, hB);
                w = *(const uint4*)&whh1_w[(u1 * 4 + 3) * 512 + ln1 * 4];       DOT4(a3, w, hA);
                w = *(const uint4*)&whh1_w[(u1 * 4 + 3) * 512 + ln1 * 4 + 256]; DOT4(a3, w, hB);
            }
            #pragma unroll
            for (int off = 32; off > 0; off >>= 1) {
                a0 += __shfl_down(a0, off, 64); a1 += __shfl_down(a1, off, 64);
                a2 += __shfl_down(a2, off, 64); a3 += __shfl_down(a3, off, 64);
            }
            if (ln1 == 0) {
                float iv = fsig(pc[0] + a0);
                float fv = fsig(pc[1] + a1);
                float gv = ftanh(pc[2] + a2);
                float ov = fsig(pc[3] + a3);
                c1 = fv * c1 + iv * gv;
                float h = ov * ftanh(c1);
                union { float f; uint32_t u; } x; x.f = h;
                __hip_atomic_store(&comm1[(size_t)s * H1 + blk * 4 + u1], x.u,
                                   __ATOMIC_RELAXED, __HIP_MEMORY_SCOPE_AGENT);
            }
        }

        // ---- pre2[s-1] = this block's 32 wih2 rows · h1[s-1] ----
        float pb[8];
        if (s >= 1) {
            float pv[8];
            #pragma unroll
            for (int d = 0; d < 8; ++d) pv[d] = 0.f;
            #pragma unroll
            for (int d = 0; d < 8; ++d) {
                int r = wv * 8 + d;
                uint4 w0 = *(const uint4*)&wih2_w[r * 512 + ln1 * 4];
                uint4 w1 = *(const uint4*)&wih2_w[r * 512 + ln1 * 4 + 256];
                DOT4(pv[d], w0, hA);
                DOT4(pv[d], w1, hB);
            }
            #pragma unroll
            for (int off = 32; off > 0; off >>= 1) {
                #pragma unroll
                for (int d = 0; d < 8; ++d) pv[d] += __shfl_down(pv[d], off, 64);
            }
            #pragma unroll
            for (int d = 0; d < 8; ++d) pb[d] = __shfl(pv[d], 0, 64);
        }

        // ---- Phase B': poll h2[s-2], stage packed f16 ----
        if (s >= 2) {
            const uint64_t* s2 = (const uint64_t*)(comm2 + (size_t)(s - 2) * H2);
            uint64_t q[4];
            for (;;) {
                #pragma unroll
                for (int k = 0; k < 4; ++k)
                    q[k] = __hip_atomic_load(&s2[tid + k * 256], __ATOMIC_RELAXED,
                                             __HIP_MEMORY_SCOPE_AGENT);
                bool bad = false;
                #pragma unroll
                for (int k = 0; k < 4; ++k)
                    bad |= ((uint32_t)q[k] == SENT) | ((uint32_t)(q[k] >> 32) == SENT);
                if (!bad) break;
                __builtin_amdgcn_s_sleep(1);
            }
            uint32_t* d = h2b + (s & 1) * 1024;
            #pragma unroll
            for (int k = 0; k < 4; ++k) {
                union { uint64_t q; float f[2]; } x; x.q = q[k];
                d[tid + k * 256] = pack_f16(x.f[0], x.f[1]);
            }
        }
        __syncthreads();   // barrier B

        // ---- Phase C: h2[s-1] ----
        if (s >= 1) {
            float b0 = 0.f, b1 = 0.f, b2 = 0.f, b3 = 0.f;
            if (s >= 2) {
                const uint32_t* h2p = h2b + (s & 1) * 1024;
                #pragma unroll
                for (int j = 0; j < 8; ++j) {
                    uint4 hx = *(const uint4*)&h2p[ln2 * 4 + j * 128];
                    uint4 w0 = *(const uint4*)&whh2_w[u2l * 1024 + ln2 * 4 + j * 128];
                    DOT4(b0, w0, hx);
                    DOT4(b1, wreg[j], hx);
                    DOT4(b2, wreg[8 + j], hx);
                    DOT4(b3, wreg[16 + j], hx);
                }
            }
            #pragma unroll
            for (int off = 16; off > 0; off >>= 1) {
                b0 += __shfl_down(b0, off, 32); b1 += __shfl_down(b1, off, 32);
                b2 += __shfl_down(b2, off, 32); b3 += __shfl_down(b3, off, 32);
            }
            if (ln2 == 0) {
                int half = u2l & 1;
                float iv = fsig(pb[half * 4 + 0] + b2g[0] + b0);
                float fv = fsig(pb[half * 4 + 1] + b2g[1] + b1);
                float gv = ftanh(pb[half * 4 + 2] + b2g[2] + b2);
                float ov = fsig(pb[half * 4 + 3] + b2g[3] + b3);
                c2 = fv * c2 + iv * gv;
                float h = ov * ftanh(c2);
                union { float f; uint32_t u; } x; x.f = h;
                __hip_atomic_store(&comm2[(size_t)(s - 1) * H2 + blk * 8 + u2l], x.u,
                                   __ATOMIC_RELAXED, __HIP_MEMORY_SCOPE_AGENT);
            }
        }

        #pragma unroll
        for (int g = 0; g < 4; ++g) pc[g] = pn[g];
    }
}

// ---------------- small matvec ----------------
__global__ __launch_bounds__(256) void linear_vec_kernel(const float* __restrict__ W,
                                                         const float* __restrict__ bias,
                                                         const float* __restrict__ x,
                                                         float* __restrict__ out,
                                                         int N, int K) {
    int wave = threadIdx.x >> 6;
    int lane = threadIdx.x & 63;
    int j = blockIdx.x * 4 + wave;
    if (j >= N) return;
    const float* wr = W + (size_t)j * K;
    float s = 0.0f;
    for (int k = lane; k < K; k += 64) s += wr[k] * x[k];
    #pragma unroll
    for (int off = 32; off > 0; off >>= 1) s += __shfl_down(s, off, 64);
    if (lane == 0) out[j] = s + bias[j];
}

extern "C" void kernel_launch(void* const* d_in, const int* in_sizes, int n_in,
                              void* d_out, int out_size, void* d_ws, size_t ws_size,
                              hipStream_t stream) {
    const float* x_f    = (const float*)d_in[0];
    const float* wih1_f = (const float*)d_in[1];
    const float* whh1_f = (const float*)d_in[2];
    const float* bih1   = (const float*)d_in[3];
    const float* bhh1   = (const float*)d_in[4];
    const float* wih2_f = (const float*)d_in[5];
    const float* whh2_f = (const float*)d_in[6];
    const float* bih2   = (const float*)d_in[7];
    const float* bhh2   = (const float*)d_in[8];
    const float* wl1    = (const float*)d_in[9];
    const float* bl1    = (const float*)d_in[10];
    const float* wl2    = (const float*)d_in[11];
    const float* bl2    = (const float*)d_in[12];

    uint8_t* base = (uint8_t*)d_ws;
    size_t off = 0;
    auto alloc = [&](size_t bytes) { size_t o = off; off = (off + bytes + 255) & ~(size_t)255; return o; };

    size_t pre1_off  = alloc((size_t)T_SEQ * G1 * 2);   // f16 [T,4096]
    size_t comm1_off = alloc((size_t)T_SEQ * H1 * 4);   // f32 [T,1024]
    size_t comm2_off = alloc((size_t)T_SEQ * H2 * 4);   // f32 [T,2048]
    size_t whh1_off  = alloc((size_t)G1 * H1 * 2);
    size_t whh2_off  = alloc((size_t)G2 * H2 * 2);
    size_t wih1_off  = alloc((size_t)G1 * IN_SZ * 2);
    size_t wih2_off  = alloc((size_t)G2 * H1 * 2);
    size_t xb_off    = alloc((size_t)T_SEQ * IN_SZ * 2);
    size_t p1_off    = alloc((size_t)L1OUT * 4);

    f16_t*    pre1  = (f16_t*)(base + pre1_off);
    uint32_t* comm1 = (uint32_t*)(base + comm1_off);
    uint32_t* comm2 = (uint32_t*)(base + comm2_off);
    ushort_t* whh1h = (ushort_t*)(base + whh1_off);
    ushort_t* whh2h = (ushort_t*)(base + whh2_off);
    f16_t*    wih1h = (f16_t*)(base + wih1_off);
    ushort_t* wih2h = (ushort_t*)(base + wih2_off);
    f16_t*    xb    = (f16_t*)(base + xb_off);
    float*    p1    = (float*)(base + p1_off);

    // poison sentinel comm buffers (data-as-signal)
    (void)hipMemsetAsync(comm1, 0xAA, (size_t)T_SEQ * H1 * 4, stream);
    (void)hipMemsetAsync(comm2, 0xAA, (size_t)T_SEQ * H2 * 4, stream);

    // f32 -> f16 conversions
    cvt_f16_kernel<<<2048, 256, 0, stream>>>(x_f,    xb,            T_SEQ * IN_SZ);
    cvt_f16_kernel<<<2048, 256, 0, stream>>>(wih1_f, wih1h,         G1 * IN_SZ);
    cvt_f16_kernel<<<2048, 256, 0, stream>>>(whh1_f, (f16_t*)whh1h, G1 * H1);
    cvt_f16_kernel<<<2048, 256, 0, stream>>>(wih2_f, (f16_t*)wih2h, G2 * H1);
    cvt_f16_kernel<<<4096, 256, 0, stream>>>(whh2_f, (f16_t*)whh2h, G2 * H2);

    // pre1 = x @ wih1^T + (bih1 + bhh1)   [f16 out]
    {
        dim3 grid(G1 / 64, T_SEQ / 64);
        gemm_bt_kernel<<<grid, 256, 0, stream>>>(xb, wih1h, pre1, bih1, bhh1,
                                                 T_SEQ, G1, IN_SZ);
    }

    // fused 2-layer recurrence: 256 blocks, 140KB dynamic LDS
    {
        size_t shmem = (size_t)(16 * 512 + 32 * 512 + 8 * 1024 + 2 * 512 + 2 * 1024) * 4;
        fused_lstm_kernel<<<256, 256, shmem, stream>>>(
            pre1, whh1h, wih2h, whh2h, bih2, bhh2, comm1, comm2, T_SEQ);
    }

    // p1 = wl1 . h2[T-1] + bl1 ; out = wl2 . p1 + bl2
    const float* h2_last = (const float*)(comm2 + (size_t)(T_SEQ - 1) * H2);
    linear_vec_kernel<<<L1OUT / 4, 256, 0, stream>>>(wl1, bl1, h2_last, p1, L1OUT, H2);
    linear_vec_kernel<<<OUT_SZ / 4, 256, 0, stream>>>(wl2, bl2, p1, (float*)d_out, OUT_SZ, L1OUT);

    (void)in_sizes; (void)n_in; (void)out_size; (void)ws_size;
}